// Round 1
// baseline (1045.207 us; speedup 1.0000x reference)
//
#include <hip/hip_runtime.h>
#include <math.h>

#define NNODE 50000
#define NEDGE 800000
#define DIM   128
#define NHEAD 4

// ---------------------------------------------------------------------------
// CSR build: histogram -> scan -> scatter
// ---------------------------------------------------------------------------
__global__ void hist_kernel(const int* __restrict__ dst, int n, int* __restrict__ deg) {
    int i = blockIdx.x * blockDim.x + threadIdx.x;
    if (i < n) atomicAdd(&deg[dst[i]], 1);
}

// single block, 1024 threads. deg (in) == cur (out, exclusive prefix), ptr gets prefix + total.
__global__ void scan_kernel(int* __restrict__ cur, int* __restrict__ ptr, int n) {
    __shared__ int tmp[1024];
    __shared__ int carry_s;
    if (threadIdx.x == 0) carry_s = 0;
    __syncthreads();
    for (int base = 0; base < n; base += 1024) {
        int i = base + threadIdx.x;
        int v = (i < n) ? cur[i] : 0;
        tmp[threadIdx.x] = v;
        __syncthreads();
        for (int off = 1; off < 1024; off <<= 1) {
            int add = (threadIdx.x >= off) ? tmp[threadIdx.x - off] : 0;
            __syncthreads();
            tmp[threadIdx.x] += add;
            __syncthreads();
        }
        int excl = tmp[threadIdx.x] - v;
        int c = carry_s;
        if (i < n) { ptr[i] = c + excl; cur[i] = c + excl; }
        __syncthreads();
        if (threadIdx.x == 1023) carry_s = c + tmp[1023];
        __syncthreads();
    }
    if (threadIdx.x == 0) ptr[n] = carry_s;
}

__global__ void scatter_kernel(const int* __restrict__ src, const int* __restrict__ dst,
                               int n, int* __restrict__ cur, int* __restrict__ out) {
    int i = blockIdx.x * blockDim.x + threadIdx.x;
    if (i < n) {
        int pos = atomicAdd(&cur[dst[i]], 1);
        out[pos] = src[i];
    }
}

// ---------------------------------------------------------------------------
// Transform: HS = X @ W ; AS[n,h] = sum_c HS[n,h*32+c]*a_src[h,c]
//            AD[n,h] = sum_k X[n,k] * (sum_c Wd[k,h*32+c]*a_dst[h,c])
// block = 512 threads (8 waves), 64 rows per tile, grid-stride over tiles.
// Each wave: 8 rows x 128 cols; each lane: 4 rows x 4 cols register tile.
// ---------------------------------------------------------------------------
__global__ __launch_bounds__(512) void transform_kernel(
    const float* __restrict__ X, const float* __restrict__ W,
    const float* __restrict__ a_src, const float* __restrict__ Wd,
    const float* __restrict__ a_dst, float* __restrict__ HS,
    float* __restrict__ AS, float* __restrict__ AD, int N)
{
    __shared__ float Ws[DIM * DIM];        // 64 KB, Ws[k*128 + j]
    __shared__ float xs[64][DIM + 4];      // padded rows (33.8 KB)
    __shared__ float wad[DIM][NHEAD];      // 2 KB
    __shared__ float asv[NHEAD][32];

    // stage W
    for (int i = threadIdx.x; i < DIM * DIM / 4; i += 512)
        ((float4*)Ws)[i] = ((const float4*)W)[i];
    // fold Wd with a_dst -> wad[k][h]
    {
        int k = threadIdx.x >> 2, h = threadIdx.x & 3;
        float s = 0.f;
        #pragma unroll 8
        for (int c = 0; c < 32; c++) s += Wd[k * DIM + h * 32 + c] * a_dst[h * 32 + c];
        wad[k][h] = s;
    }
    if (threadIdx.x < DIM) asv[threadIdx.x >> 5][threadIdx.x & 31] = a_src[threadIdx.x];
    __syncthreads();

    const int wave = threadIdx.x >> 6;
    const int lane = threadIdx.x & 63;
    const int half = lane >> 5;
    const int li   = lane & 31;
    const int c    = li * 4;        // output col base
    const int hh   = li >> 3;       // head for AS

    for (int tile = blockIdx.x * 64; tile < N; tile += gridDim.x * 64) {
        __syncthreads();  // protect xs from previous iteration readers
        // stage 64 rows of X
        for (int i = threadIdx.x; i < 64 * 32; i += 512) {
            int r = i >> 5, cc = i & 31;
            int row = tile + r;
            float4 v = (row < N) ? ((const float4*)(X + (size_t)row * DIM))[cc]
                                 : make_float4(0.f, 0.f, 0.f, 0.f);
            *(float4*)&xs[r][cc * 4] = v;
        }
        __syncthreads();

        const int r0 = wave * 8 + half * 4;
        float4 acc0 = make_float4(0,0,0,0), acc1 = acc0, acc2 = acc0, acc3 = acc0;
        #pragma unroll 4
        for (int kk = 0; kk < DIM; kk += 4) {
            float4 x0 = *(const float4*)&xs[r0 + 0][kk];
            float4 x1 = *(const float4*)&xs[r0 + 1][kk];
            float4 x2 = *(const float4*)&xs[r0 + 2][kk];
            float4 x3 = *(const float4*)&xs[r0 + 3][kk];
            float4 w0 = *(const float4*)&Ws[(kk + 0) * DIM + c];
            float4 w1 = *(const float4*)&Ws[(kk + 1) * DIM + c];
            float4 w2 = *(const float4*)&Ws[(kk + 2) * DIM + c];
            float4 w3 = *(const float4*)&Ws[(kk + 3) * DIM + c];
            acc0.x += x0.x*w0.x + x0.y*w1.x + x0.z*w2.x + x0.w*w3.x;
            acc0.y += x0.x*w0.y + x0.y*w1.y + x0.z*w2.y + x0.w*w3.y;
            acc0.z += x0.x*w0.z + x0.y*w1.z + x0.z*w2.z + x0.w*w3.z;
            acc0.w += x0.x*w0.w + x0.y*w1.w + x0.z*w2.w + x0.w*w3.w;
            acc1.x += x1.x*w0.x + x1.y*w1.x + x1.z*w2.x + x1.w*w3.x;
            acc1.y += x1.x*w0.y + x1.y*w1.y + x1.z*w2.y + x1.w*w3.y;
            acc1.z += x1.x*w0.z + x1.y*w1.z + x1.z*w2.z + x1.w*w3.z;
            acc1.w += x1.x*w0.w + x1.y*w1.w + x1.z*w2.w + x1.w*w3.w;
            acc2.x += x2.x*w0.x + x2.y*w1.x + x2.z*w2.x + x2.w*w3.x;
            acc2.y += x2.x*w0.y + x2.y*w1.y + x2.z*w2.y + x2.w*w3.y;
            acc2.z += x2.x*w0.z + x2.y*w1.z + x2.z*w2.z + x2.w*w3.z;
            acc2.w += x2.x*w0.w + x2.y*w1.w + x2.z*w2.w + x2.w*w3.w;
            acc3.x += x3.x*w0.x + x3.y*w1.x + x3.z*w2.x + x3.w*w3.x;
            acc3.y += x3.x*w0.y + x3.y*w1.y + x3.z*w2.y + x3.w*w3.y;
            acc3.z += x3.x*w0.z + x3.y*w1.z + x3.z*w2.z + x3.w*w3.z;
            acc3.w += x3.x*w0.w + x3.y*w1.w + x3.z*w2.w + x3.w*w3.w;
        }

        // epilogue: store HS and reduce AS
        float4 accs[4] = {acc0, acc1, acc2, acc3};
        float a0 = asv[hh][(c & 31) + 0], a1 = asv[hh][(c & 31) + 1];
        float a2 = asv[hh][(c & 31) + 2], a3 = asv[hh][(c & 31) + 3];
        #pragma unroll
        for (int r = 0; r < 4; r++) {
            int row = tile + r0 + r;
            if (row < N) *(float4*)&HS[(size_t)row * DIM + c] = accs[r];
            float v = accs[r].x * a0 + accs[r].y * a1 + accs[r].z * a2 + accs[r].w * a3;
            v += __shfl_xor(v, 1);
            v += __shfl_xor(v, 2);
            v += __shfl_xor(v, 4);
            if ((li & 7) == 0 && row < N) AS[row * NHEAD + hh] = v;
        }

        // AD: lane -> (row rr, head hd), two lanes split the k range
        {
            int p  = lane >> 1;
            int rr = p >> 2;
            int hd = p & 3;
            int row = tile + wave * 8 + rr;
            int k0 = (lane & 1) * 64;
            float s = 0.f;
            #pragma unroll 8
            for (int k = k0; k < k0 + 64; k++) s += xs[wave * 8 + rr][k] * wad[k][hd];
            s += __shfl_xor(s, 1);
            if ((lane & 1) == 0 && row < N) AD[row * NHEAD + hd] = s;
        }
    }
}

// ---------------------------------------------------------------------------
// Aggregation: one wave per dst node, online softmax over its CSR edge list.
// lane covers cols [2*lane, 2*lane+1], head = lane>>4. Fuses bias + ELU.
// ---------------------------------------------------------------------------
__global__ __launch_bounds__(256) void agg_kernel(
    const float* __restrict__ HS, const float* __restrict__ AS,
    const float* __restrict__ AD, const int* __restrict__ ptr,
    const int* __restrict__ srcs, const float* __restrict__ bias,
    float* __restrict__ out, int Nd)
{
    int wave = threadIdx.x >> 6;
    int lane = threadIdx.x & 63;
    int d = blockIdx.x * 4 + wave;
    if (d >= Nd) return;
    int j0 = lane * 2;
    int hh = lane >> 4;
    float adh = AD[d * NHEAD + hh];
    int e0 = ptr[d], e1 = ptr[d + 1];
    float m = -INFINITY, l = 0.f, acc0 = 0.f, acc1 = 0.f;
    for (int e = e0; e < e1; e++) {
        int s = srcs[e];
        float a = AS[s * NHEAD + hh] + adh;
        a = a > 0.f ? a : 0.2f * a;                 // leaky_relu(0.2)
        float mn = fmaxf(m, a);
        float scale = __expf(m - mn);               // m=-inf first iter -> 0
        float p = __expf(a - mn);
        float2 h2 = *(const float2*)&HS[(size_t)s * DIM + j0];
        acc0 = acc0 * scale + p * h2.x;
        acc1 = acc1 * scale + p * h2.y;
        l = l * scale + p;
        m = mn;
    }
    float inv = 1.f / (l + 1e-16f);
    float o0 = acc0 * inv + bias[j0];
    float o1 = acc1 * inv + bias[j0 + 1];
    o0 = o0 > 0.f ? o0 : expf(o0) - 1.f;            // ELU
    o1 = o1 > 0.f ? o1 : expf(o1) - 1.f;
    *(float2*)&out[(size_t)d * DIM + j0] = make_float2(o0, o1);
}

// ---------------------------------------------------------------------------
extern "C" void kernel_launch(void* const* d_in, const int* in_sizes, int n_in,
                              void* d_out, int out_size, void* d_ws, size_t ws_size,
                              hipStream_t stream) {
    const float* x_food      = (const float*)d_in[0];
    const float* x_nut       = (const float*)d_in[1];
    const float* Wsrc_fn     = (const float*)d_in[2];
    const float* Wdst_fn     = (const float*)d_in[3];
    const float* att_src_fn  = (const float*)d_in[4];
    const float* att_dst_fn  = (const float*)d_in[5];
    const float* bias_fn     = (const float*)d_in[6];
    const float* Wsrc_nf     = (const float*)d_in[7];
    const float* Wdst_nf     = (const float*)d_in[8];
    const float* att_src_nf  = (const float*)d_in[9];
    const float* att_dst_nf  = (const float*)d_in[10];
    const float* bias_nf     = (const float*)d_in[11];
    const int*   ei_fn       = (const int*)d_in[12];  // [2,E] src,dst
    const int*   ei_nf       = (const int*)d_in[13];
    float* out = (float*)d_out;

    // workspace layout (all element counts multiples of 4)
    char* ws = (char*)d_ws;
    size_t off = 0;
    auto alloc_f = [&](size_t nelem) { float* p = (float*)(ws + off); off += nelem * 4; return p; };
    auto alloc_i = [&](size_t nelem) { int* p = (int*)(ws + off); off += nelem * 4; return p; };

    float* HS_fn  = alloc_f((size_t)NNODE * DIM);
    float* HS_nf  = alloc_f((size_t)NNODE * DIM);
    float* B_food = alloc_f((size_t)NNODE * DIM);
    float* B_nut  = alloc_f((size_t)NNODE * DIM);
    float* AS_fn  = alloc_f(NNODE * NHEAD);
    float* AS_nf  = alloc_f(NNODE * NHEAD);
    float* AD_fn  = alloc_f(NNODE * NHEAD);
    float* AD_nf  = alloc_f(NNODE * NHEAD);
    int* ptr_fn  = alloc_i(50004);
    int* ptr_nf  = alloc_i(50004);
    int* cur_fn  = alloc_i(NNODE);
    int* cur_nf  = alloc_i(NNODE);
    int* srcs_fn = alloc_i(NEDGE);
    int* srcs_nf = alloc_i(NEDGE);

    // ---- CSR build (edges constant across layers) ----
    hipMemsetAsync(cur_fn, 0, NNODE * 4, stream);
    hipMemsetAsync(cur_nf, 0, NNODE * 4, stream);
    int egrid = (NEDGE + 255) / 256;
    hist_kernel<<<egrid, 256, 0, stream>>>(ei_fn + NEDGE, NEDGE, cur_fn);
    hist_kernel<<<egrid, 256, 0, stream>>>(ei_nf + NEDGE, NEDGE, cur_nf);
    scan_kernel<<<1, 1024, 0, stream>>>(cur_fn, ptr_fn, NNODE);
    scan_kernel<<<1, 1024, 0, stream>>>(cur_nf, ptr_nf, NNODE);
    scatter_kernel<<<egrid, 256, 0, stream>>>(ei_fn, ei_fn + NEDGE, NEDGE, cur_fn, srcs_fn);
    scatter_kernel<<<egrid, 256, 0, stream>>>(ei_nf, ei_nf + NEDGE, NEDGE, cur_nf, srcs_nf);

    const int WL = DIM * DIM;   // per-layer W stride
    const int AL = NHEAD * 32;  // per-layer att stride
    int agrid = (NNODE + 3) / 4;

    // ---- Layer 0 (inputs: x_food, x_nut) ----
    transform_kernel<<<256, 512, 0, stream>>>(x_food, Wsrc_fn, att_src_fn,
                                              Wdst_nf, att_dst_nf, HS_fn, AS_fn, AD_nf, NNODE);
    transform_kernel<<<256, 512, 0, stream>>>(x_nut, Wsrc_nf, att_src_nf,
                                              Wdst_fn, att_dst_fn, HS_nf, AS_nf, AD_fn, NNODE);
    agg_kernel<<<agrid, 256, 0, stream>>>(HS_fn, AS_fn, AD_fn, ptr_fn, srcs_fn,
                                          bias_fn, B_nut, NNODE);   // dst = nut
    agg_kernel<<<agrid, 256, 0, stream>>>(HS_nf, AS_nf, AD_nf, ptr_nf, srcs_nf,
                                          bias_nf, B_food, NNODE);  // dst = food

    // ---- Layer 1 (inputs: B_food, B_nut) -> d_out ----
    transform_kernel<<<256, 512, 0, stream>>>(B_food, Wsrc_fn + WL, att_src_fn + AL,
                                              Wdst_nf + WL, att_dst_nf + AL, HS_fn, AS_fn, AD_nf, NNODE);
    transform_kernel<<<256, 512, 0, stream>>>(B_nut, Wsrc_nf + WL, att_src_nf + AL,
                                              Wdst_fn + WL, att_dst_fn + AL, HS_nf, AS_nf, AD_fn, NNODE);
    agg_kernel<<<agrid, 256, 0, stream>>>(HS_fn, AS_fn, AD_fn, ptr_fn, srcs_fn,
                                          bias_fn + DIM, out + (size_t)NNODE * DIM, NNODE); // h_nut
    agg_kernel<<<agrid, 256, 0, stream>>>(HS_nf, AS_nf, AD_nf, ptr_nf, srcs_nf,
                                          bias_nf + DIM, out, NNODE);                       // h_food
}

// Round 2
// 773.422 us; speedup vs baseline: 1.3514x; 1.3514x over previous
//
#include <hip/hip_runtime.h>
#include <math.h>

#define NNODE 50000
#define NEDGE 800000
#define DIM   128
#define NHEAD 4

// ---------------------------------------------------------------------------
// CSR build: histogram -> two-level scan -> scatter
// ---------------------------------------------------------------------------
__global__ void hist_kernel(const int* __restrict__ dst, int n, int* __restrict__ deg) {
    int i = blockIdx.x * blockDim.x + threadIdx.x;
    if (i < n) atomicAdd(&deg[dst[i]], 1);
}

// grid = ceil(n/256); block sums -> bsum[b]
__global__ void scan_partial(const int* __restrict__ deg, int n, int* __restrict__ bsum) {
    __shared__ int ws[4];
    int i = blockIdx.x * 256 + threadIdx.x;
    int v = (i < n) ? deg[i] : 0;
    #pragma unroll
    for (int off = 1; off < 64; off <<= 1) v += __shfl_xor(v, off);
    if ((threadIdx.x & 63) == 0) ws[threadIdx.x >> 6] = v;
    __syncthreads();
    if (threadIdx.x == 0) bsum[blockIdx.x] = ws[0] + ws[1] + ws[2] + ws[3];
}

// 1 block, 256 threads; nb <= 256. Exclusive-scan bsum in place; total -> ptr[n].
__global__ void scan_top(int* __restrict__ bsum, int nb, int* __restrict__ ptr, int n) {
    __shared__ int tmp[256];
    int t = threadIdx.x;
    int v = (t < nb) ? bsum[t] : 0;
    tmp[t] = v;
    __syncthreads();
    for (int off = 1; off < 256; off <<= 1) {
        int add = (t >= off) ? tmp[t - off] : 0;
        __syncthreads();
        tmp[t] += add;
        __syncthreads();
    }
    if (t < nb) bsum[t] = tmp[t] - v;
    if (t == 255) ptr[n] = tmp[255];
}

// grid = ceil(n/256): per-block exclusive scan + block offset; writes ptr & cur.
__global__ void scan_final(const int* __restrict__ boff, int n,
                           int* __restrict__ cur, int* __restrict__ ptr) {
    __shared__ int tmp[256];
    int i = blockIdx.x * 256 + threadIdx.x;
    int t = threadIdx.x;
    int v = (i < n) ? cur[i] : 0;
    tmp[t] = v;
    __syncthreads();
    for (int off = 1; off < 256; off <<= 1) {
        int add = (t >= off) ? tmp[t - off] : 0;
        __syncthreads();
        tmp[t] += add;
        __syncthreads();
    }
    int excl = tmp[t] - v + boff[blockIdx.x];
    if (i < n) { ptr[i] = excl; cur[i] = excl; }
}

__global__ void scatter_kernel(const int* __restrict__ src, const int* __restrict__ dst,
                               int n, int* __restrict__ cur, int* __restrict__ out) {
    int i = blockIdx.x * blockDim.x + threadIdx.x;
    if (i < n) {
        int pos = atomicAdd(&cur[dst[i]], 1);
        out[pos] = src[i];
    }
}

// ---------------------------------------------------------------------------
// Transform: HS = X @ W ; AS[n,h] = sum_c HS[n,h*32+c]*a_src[h,c]
//            AD[n,h] = sum_k X[n,k] * (sum_c Wd[k,h*32+c]*a_dst[h,c])
// ---------------------------------------------------------------------------
__global__ __launch_bounds__(512) void transform_kernel(
    const float* __restrict__ X, const float* __restrict__ W,
    const float* __restrict__ a_src, const float* __restrict__ Wd,
    const float* __restrict__ a_dst, float* __restrict__ HS,
    float* __restrict__ AS, float* __restrict__ AD, int N)
{
    __shared__ float Ws[DIM * DIM];        // 64 KB
    __shared__ float xs[64][DIM + 4];      // padded rows
    __shared__ float wad[DIM][NHEAD];
    __shared__ float asv[NHEAD][32];

    for (int i = threadIdx.x; i < DIM * DIM / 4; i += 512)
        ((float4*)Ws)[i] = ((const float4*)W)[i];
    {
        int k = threadIdx.x >> 2, h = threadIdx.x & 3;
        float s = 0.f;
        #pragma unroll 8
        for (int c = 0; c < 32; c++) s += Wd[k * DIM + h * 32 + c] * a_dst[h * 32 + c];
        wad[k][h] = s;
    }
    if (threadIdx.x < DIM) asv[threadIdx.x >> 5][threadIdx.x & 31] = a_src[threadIdx.x];
    __syncthreads();

    const int wave = threadIdx.x >> 6;
    const int lane = threadIdx.x & 63;
    const int half = lane >> 5;
    const int li   = lane & 31;
    const int c    = li * 4;
    const int hh   = li >> 3;

    for (int tile = blockIdx.x * 64; tile < N; tile += gridDim.x * 64) {
        __syncthreads();
        for (int i = threadIdx.x; i < 64 * 32; i += 512) {
            int r = i >> 5, cc = i & 31;
            int row = tile + r;
            float4 v = (row < N) ? ((const float4*)(X + (size_t)row * DIM))[cc]
                                 : make_float4(0.f, 0.f, 0.f, 0.f);
            *(float4*)&xs[r][cc * 4] = v;
        }
        __syncthreads();

        const int r0 = wave * 8 + half * 4;
        float4 acc0 = make_float4(0,0,0,0), acc1 = acc0, acc2 = acc0, acc3 = acc0;
        #pragma unroll 4
        for (int kk = 0; kk < DIM; kk += 4) {
            float4 x0 = *(const float4*)&xs[r0 + 0][kk];
            float4 x1 = *(const float4*)&xs[r0 + 1][kk];
            float4 x2 = *(const float4*)&xs[r0 + 2][kk];
            float4 x3 = *(const float4*)&xs[r0 + 3][kk];
            float4 w0 = *(const float4*)&Ws[(kk + 0) * DIM + c];
            float4 w1 = *(const float4*)&Ws[(kk + 1) * DIM + c];
            float4 w2 = *(const float4*)&Ws[(kk + 2) * DIM + c];
            float4 w3 = *(const float4*)&Ws[(kk + 3) * DIM + c];
            acc0.x += x0.x*w0.x + x0.y*w1.x + x0.z*w2.x + x0.w*w3.x;
            acc0.y += x0.x*w0.y + x0.y*w1.y + x0.z*w2.y + x0.w*w3.y;
            acc0.z += x0.x*w0.z + x0.y*w1.z + x0.z*w2.z + x0.w*w3.z;
            acc0.w += x0.x*w0.w + x0.y*w1.w + x0.z*w2.w + x0.w*w3.w;
            acc1.x += x1.x*w0.x + x1.y*w1.x + x1.z*w2.x + x1.w*w3.x;
            acc1.y += x1.x*w0.y + x1.y*w1.y + x1.z*w2.y + x1.w*w3.y;
            acc1.z += x1.x*w0.z + x1.y*w1.z + x1.z*w2.z + x1.w*w3.z;
            acc1.w += x1.x*w0.w + x1.y*w1.w + x1.z*w2.w + x1.w*w3.w;
            acc2.x += x2.x*w0.x + x2.y*w1.x + x2.z*w2.x + x2.w*w3.x;
            acc2.y += x2.x*w0.y + x2.y*w1.y + x2.z*w2.y + x2.w*w3.y;
            acc2.z += x2.x*w0.z + x2.y*w1.z + x2.z*w2.z + x2.w*w3.z;
            acc2.w += x2.x*w0.w + x2.y*w1.w + x2.z*w2.w + x2.w*w3.w;
            acc3.x += x3.x*w0.x + x3.y*w1.x + x3.z*w2.x + x3.w*w3.x;
            acc3.y += x3.x*w0.y + x3.y*w1.y + x3.z*w2.y + x3.w*w3.y;
            acc3.z += x3.x*w0.z + x3.y*w1.z + x3.z*w2.z + x3.w*w3.z;
            acc3.w += x3.x*w0.w + x3.y*w1.w + x3.z*w2.w + x3.w*w3.w;
        }

        float4 accs[4] = {acc0, acc1, acc2, acc3};
        float a0 = asv[hh][(c & 31) + 0], a1 = asv[hh][(c & 31) + 1];
        float a2 = asv[hh][(c & 31) + 2], a3 = asv[hh][(c & 31) + 3];
        #pragma unroll
        for (int r = 0; r < 4; r++) {
            int row = tile + r0 + r;
            if (row < N) *(float4*)&HS[(size_t)row * DIM + c] = accs[r];
            float v = accs[r].x * a0 + accs[r].y * a1 + accs[r].z * a2 + accs[r].w * a3;
            v += __shfl_xor(v, 1);
            v += __shfl_xor(v, 2);
            v += __shfl_xor(v, 4);
            if ((li & 7) == 0 && row < N) AS[row * NHEAD + hh] = v;
        }

        {
            int p  = lane >> 1;
            int rr = p >> 2;
            int hd = p & 3;
            int row = tile + wave * 8 + rr;
            int k0 = (lane & 1) * 64;
            float s = 0.f;
            #pragma unroll 8
            for (int k = k0; k < k0 + 64; k++) s += xs[wave * 8 + rr][k] * wad[k][hd];
            s += __shfl_xor(s, 1);
            if ((lane & 1) == 0 && row < N) AD[row * NHEAD + hd] = s;
        }
    }
}

// ---------------------------------------------------------------------------
// Aggregation: one wave per dst node, TWO-PASS softmax.
// Pass 1: m_raw = max_e AS[src,h]  (leaky_relu monotonic -> apply at end).
// Pass 2: independent, 4x-unrolled accumulation (pipelined HS loads).
// ---------------------------------------------------------------------------
__global__ __launch_bounds__(256) void agg_kernel(
    const float* __restrict__ HS, const float* __restrict__ AS,
    const float* __restrict__ AD, const int* __restrict__ ptr,
    const int* __restrict__ srcs, const float* __restrict__ bias,
    float* __restrict__ out, int Nd)
{
    int wave = threadIdx.x >> 6;
    int lane = threadIdx.x & 63;
    int d = blockIdx.x * 4 + wave;
    if (d >= Nd) return;
    int j0 = lane * 2;
    int hh = lane >> 4;
    float adh = AD[d * NHEAD + hh];
    int e0 = ptr[d], e1 = ptr[d + 1];

    // ---- pass 1: raw max of AS over segment ----
    float rm = -INFINITY;
    {
        int e = e0;
        for (; e + 4 <= e1; e += 4) {
            int s0 = srcs[e], s1 = srcs[e+1], s2 = srcs[e+2], s3 = srcs[e+3];
            float v0 = AS[s0 * NHEAD + hh];
            float v1 = AS[s1 * NHEAD + hh];
            float v2 = AS[s2 * NHEAD + hh];
            float v3 = AS[s3 * NHEAD + hh];
            rm = fmaxf(rm, fmaxf(fmaxf(v0, v1), fmaxf(v2, v3)));
        }
        for (; e < e1; e++) rm = fmaxf(rm, AS[srcs[e] * NHEAD + hh]);
    }
    float araw = rm + adh;
    float m = araw > 0.f ? araw : 0.2f * araw;   // lrelu(max) == max(lrelu)

    // ---- pass 2: independent accumulation ----
    float l0 = 0.f, l1 = 0.f, l2 = 0.f, l3 = 0.f;
    float ax0 = 0.f, ay0 = 0.f, ax1 = 0.f, ay1 = 0.f;
    float ax2 = 0.f, ay2 = 0.f, ax3 = 0.f, ay3 = 0.f;
    {
        int e = e0;
        for (; e + 4 <= e1; e += 4) {
            int s0 = srcs[e], s1 = srcs[e+1], s2 = srcs[e+2], s3 = srcs[e+3];
            float v0 = AS[s0 * NHEAD + hh] + adh;
            float v1 = AS[s1 * NHEAD + hh] + adh;
            float v2 = AS[s2 * NHEAD + hh] + adh;
            float v3 = AS[s3 * NHEAD + hh] + adh;
            float2 h0 = *(const float2*)&HS[(size_t)s0 * DIM + j0];
            float2 h1 = *(const float2*)&HS[(size_t)s1 * DIM + j0];
            float2 h2 = *(const float2*)&HS[(size_t)s2 * DIM + j0];
            float2 h3 = *(const float2*)&HS[(size_t)s3 * DIM + j0];
            v0 = v0 > 0.f ? v0 : 0.2f * v0;
            v1 = v1 > 0.f ? v1 : 0.2f * v1;
            v2 = v2 > 0.f ? v2 : 0.2f * v2;
            v3 = v3 > 0.f ? v3 : 0.2f * v3;
            float p0 = __expf(v0 - m), p1 = __expf(v1 - m);
            float p2 = __expf(v2 - m), p3 = __expf(v3 - m);
            l0 += p0; l1 += p1; l2 += p2; l3 += p3;
            ax0 += p0 * h0.x; ay0 += p0 * h0.y;
            ax1 += p1 * h1.x; ay1 += p1 * h1.y;
            ax2 += p2 * h2.x; ay2 += p2 * h2.y;
            ax3 += p3 * h3.x; ay3 += p3 * h3.y;
        }
        for (; e < e1; e++) {
            int s = srcs[e];
            float v = AS[s * NHEAD + hh] + adh;
            v = v > 0.f ? v : 0.2f * v;
            float p = __expf(v - m);
            float2 h2 = *(const float2*)&HS[(size_t)s * DIM + j0];
            l0 += p; ax0 += p * h2.x; ay0 += p * h2.y;
        }
    }
    float l = (l0 + l1) + (l2 + l3);
    float accx = (ax0 + ax1) + (ax2 + ax3);
    float accy = (ay0 + ay1) + (ay2 + ay3);

    float inv = 1.f / (l + 1e-16f);
    float o0 = accx * inv + bias[j0];
    float o1 = accy * inv + bias[j0 + 1];
    o0 = o0 > 0.f ? o0 : expf(o0) - 1.f;            // ELU
    o1 = o1 > 0.f ? o1 : expf(o1) - 1.f;
    *(float2*)&out[(size_t)d * DIM + j0] = make_float2(o0, o1);
}

// ---------------------------------------------------------------------------
extern "C" void kernel_launch(void* const* d_in, const int* in_sizes, int n_in,
                              void* d_out, int out_size, void* d_ws, size_t ws_size,
                              hipStream_t stream) {
    const float* x_food      = (const float*)d_in[0];
    const float* x_nut       = (const float*)d_in[1];
    const float* Wsrc_fn     = (const float*)d_in[2];
    const float* Wdst_fn     = (const float*)d_in[3];
    const float* att_src_fn  = (const float*)d_in[4];
    const float* att_dst_fn  = (const float*)d_in[5];
    const float* bias_fn     = (const float*)d_in[6];
    const float* Wsrc_nf     = (const float*)d_in[7];
    const float* Wdst_nf     = (const float*)d_in[8];
    const float* att_src_nf  = (const float*)d_in[9];
    const float* att_dst_nf  = (const float*)d_in[10];
    const float* bias_nf     = (const float*)d_in[11];
    const int*   ei_fn       = (const int*)d_in[12];  // [2,E] src,dst
    const int*   ei_nf       = (const int*)d_in[13];
    float* out = (float*)d_out;

    char* ws = (char*)d_ws;
    size_t off = 0;
    auto alloc_f = [&](size_t nelem) { float* p = (float*)(ws + off); off += nelem * 4; return p; };
    auto alloc_i = [&](size_t nelem) { int* p = (int*)(ws + off); off += nelem * 4; return p; };

    float* HS_fn  = alloc_f((size_t)NNODE * DIM);
    float* HS_nf  = alloc_f((size_t)NNODE * DIM);
    float* B_food = alloc_f((size_t)NNODE * DIM);
    float* B_nut  = alloc_f((size_t)NNODE * DIM);
    float* AS_fn  = alloc_f(NNODE * NHEAD);
    float* AS_nf  = alloc_f(NNODE * NHEAD);
    float* AD_fn  = alloc_f(NNODE * NHEAD);
    float* AD_nf  = alloc_f(NNODE * NHEAD);
    int* ptr_fn  = alloc_i(50004);
    int* ptr_nf  = alloc_i(50004);
    int* cur_fn  = alloc_i(NNODE);
    int* cur_nf  = alloc_i(NNODE);
    int* srcs_fn = alloc_i(NEDGE);
    int* srcs_nf = alloc_i(NEDGE);
    int* bsum_fn = alloc_i(256);
    int* bsum_nf = alloc_i(256);

    // ---- CSR build ----
    hipMemsetAsync(cur_fn, 0, NNODE * 4, stream);
    hipMemsetAsync(cur_nf, 0, NNODE * 4, stream);
    int egrid = (NEDGE + 255) / 256;
    int ngrid = (NNODE + 255) / 256;   // 196
    hist_kernel<<<egrid, 256, 0, stream>>>(ei_fn + NEDGE, NEDGE, cur_fn);
    hist_kernel<<<egrid, 256, 0, stream>>>(ei_nf + NEDGE, NEDGE, cur_nf);
    scan_partial<<<ngrid, 256, 0, stream>>>(cur_fn, NNODE, bsum_fn);
    scan_partial<<<ngrid, 256, 0, stream>>>(cur_nf, NNODE, bsum_nf);
    scan_top<<<1, 256, 0, stream>>>(bsum_fn, ngrid, ptr_fn, NNODE);
    scan_top<<<1, 256, 0, stream>>>(bsum_nf, ngrid, ptr_nf, NNODE);
    scan_final<<<ngrid, 256, 0, stream>>>(bsum_fn, NNODE, cur_fn, ptr_fn);
    scan_final<<<ngrid, 256, 0, stream>>>(bsum_nf, NNODE, cur_nf, ptr_nf);
    scatter_kernel<<<egrid, 256, 0, stream>>>(ei_fn, ei_fn + NEDGE, NEDGE, cur_fn, srcs_fn);
    scatter_kernel<<<egrid, 256, 0, stream>>>(ei_nf, ei_nf + NEDGE, NEDGE, cur_nf, srcs_nf);

    const int WL = DIM * DIM;
    const int AL = NHEAD * 32;
    int agrid = (NNODE + 3) / 4;

    // ---- Layer 0 ----
    transform_kernel<<<256, 512, 0, stream>>>(x_food, Wsrc_fn, att_src_fn,
                                              Wdst_nf, att_dst_nf, HS_fn, AS_fn, AD_nf, NNODE);
    transform_kernel<<<256, 512, 0, stream>>>(x_nut, Wsrc_nf, att_src_nf,
                                              Wdst_fn, att_dst_fn, HS_nf, AS_nf, AD_fn, NNODE);
    agg_kernel<<<agrid, 256, 0, stream>>>(HS_fn, AS_fn, AD_fn, ptr_fn, srcs_fn,
                                          bias_fn, B_nut, NNODE);
    agg_kernel<<<agrid, 256, 0, stream>>>(HS_nf, AS_nf, AD_nf, ptr_nf, srcs_nf,
                                          bias_nf, B_food, NNODE);

    // ---- Layer 1 -> d_out ----
    transform_kernel<<<256, 512, 0, stream>>>(B_food, Wsrc_fn + WL, att_src_fn + AL,
                                              Wdst_nf + WL, att_dst_nf + AL, HS_fn, AS_fn, AD_nf, NNODE);
    transform_kernel<<<256, 512, 0, stream>>>(B_nut, Wsrc_nf + WL, att_src_nf + AL,
                                              Wdst_fn + WL, att_dst_fn + AL, HS_nf, AS_nf, AD_fn, NNODE);
    agg_kernel<<<agrid, 256, 0, stream>>>(HS_fn, AS_fn, AD_fn, ptr_fn, srcs_fn,
                                          bias_fn + DIM, out + (size_t)NNODE * DIM, NNODE);
    agg_kernel<<<agrid, 256, 0, stream>>>(HS_nf, AS_nf, AD_nf, ptr_nf, srcs_nf,
                                          bias_nf + DIM, out, NNODE);
}

// Round 3
// 694.828 us; speedup vs baseline: 1.5043x; 1.1131x over previous
//
#include <hip/hip_runtime.h>
#include <math.h>

#define NNODE 50000
#define NEDGE 800000
#define DIM   128
#define NHEAD 4
#define NTILE ((NNODE + 63) / 64)   // 782
#define NG    196                    // ceil(NNODE/256)

typedef __bf16 bf16x8 __attribute__((ext_vector_type(8)));
typedef float  f32x4  __attribute__((ext_vector_type(4)));

static __device__ __forceinline__ void bfsplit(float x, ushort& hi, ushort& lo) {
    __bf16 h = (__bf16)x;
    float hf = (float)h;
    __bf16 l = (__bf16)(x - hf);
    hi = __builtin_bit_cast(unsigned short, h);
    lo = __builtin_bit_cast(unsigned short, l);
}
static __device__ __forceinline__ float bf2f(ushort u) {
    unsigned v = ((unsigned)u) << 16;
    return __builtin_bit_cast(float, v);
}
static __device__ __forceinline__ ushort f2h(float x) {
    _Float16 h = (_Float16)x;
    return __builtin_bit_cast(unsigned short, h);
}
static __device__ __forceinline__ float2 up2(unsigned u) {
    _Float16 a = __builtin_bit_cast(_Float16, (unsigned short)(u & 0xffff));
    _Float16 b = __builtin_bit_cast(_Float16, (unsigned short)(u >> 16));
    return make_float2((float)a, (float)b);
}

// ---------------------------------------------------------------------------
// CSR build (both relations fused per dispatch)
// ---------------------------------------------------------------------------
__global__ void hist2(const int* __restrict__ dA, const int* __restrict__ dB,
                      int* __restrict__ cA, int* __restrict__ cB) {
    int i = blockIdx.x * 256 + threadIdx.x;
    if (i < NEDGE) atomicAdd(&cA[dA[i]], 1);
    else { i -= NEDGE; atomicAdd(&cB[dB[i]], 1); }
}

__global__ void scan_partial2(const int* __restrict__ cA, const int* __restrict__ cB,
                              int* __restrict__ bs) {  // bs[2][256]
    int rel = (int)(blockIdx.x >= NG);
    const int* c = rel ? cB : cA;
    int b = blockIdx.x - rel * NG;
    __shared__ int ws4[4];
    int i = b * 256 + threadIdx.x;
    int v = (i < NNODE) ? c[i] : 0;
    #pragma unroll
    for (int off = 1; off < 64; off <<= 1) v += __shfl_xor(v, off);
    if ((threadIdx.x & 63) == 0) ws4[threadIdx.x >> 6] = v;
    __syncthreads();
    if (threadIdx.x == 0) bs[rel * 256 + b] = ws4[0] + ws4[1] + ws4[2] + ws4[3];
}

__global__ void scan_top2(int* __restrict__ bs, int* __restrict__ ptrA, int* __restrict__ ptrB) {
    int rel = blockIdx.x;
    int* ptr = rel ? ptrB : ptrA;
    __shared__ int tmp[256];
    int t = threadIdx.x;
    int v = (t < NG) ? bs[rel * 256 + t] : 0;
    tmp[t] = v; __syncthreads();
    for (int off = 1; off < 256; off <<= 1) {
        int add = (t >= off) ? tmp[t - off] : 0; __syncthreads();
        tmp[t] += add; __syncthreads();
    }
    if (t < NG) bs[rel * 256 + t] = tmp[t] - v;
    if (t == 255) ptr[NNODE] = tmp[255];
}

__global__ void scan_final2(const int* __restrict__ bs,
                            int* __restrict__ cA, int* __restrict__ ptrA,
                            int* __restrict__ cB, int* __restrict__ ptrB) {
    int rel = (int)(blockIdx.x >= NG);
    int* c = rel ? cB : cA;
    int* ptr = rel ? ptrB : ptrA;
    int b = blockIdx.x - rel * NG;
    __shared__ int tmp[256];
    int i = b * 256 + threadIdx.x, t = threadIdx.x;
    int v = (i < NNODE) ? c[i] : 0;
    tmp[t] = v; __syncthreads();
    for (int off = 1; off < 256; off <<= 1) {
        int add = (t >= off) ? tmp[t - off] : 0; __syncthreads();
        tmp[t] += add; __syncthreads();
    }
    int excl = tmp[t] - v + bs[rel * 256 + b];
    if (i < NNODE) { ptr[i] = excl; c[i] = excl; }
}

__global__ void scatter2(const int* __restrict__ eA, const int* __restrict__ eB,
                         int* __restrict__ cA, int* __restrict__ cB,
                         int* __restrict__ sA, int* __restrict__ sB) {
    int i = blockIdx.x * 256 + threadIdx.x;
    if (i < NEDGE) { int pos = atomicAdd(&cA[eA[NEDGE + i]], 1); sA[pos] = eA[i]; }
    else { i -= NEDGE; int pos = atomicAdd(&cB[eB[NEDGE + i]], 1); sB[pos] = eB[i]; }
}

// ---------------------------------------------------------------------------
// wav[call][k][8]: cols 0..3 = was (Wsrc·a_src), 4..7 = wad (Wdst·a_dst)
// call = layer*2 + which (which 0: food-as-src, 1: nut-as-src)
// ---------------------------------------------------------------------------
__global__ void prep_wav(const float* __restrict__ Wsrc_fn, const float* __restrict__ a_src_fn,
                         const float* __restrict__ Wdst_fn, const float* __restrict__ a_dst_fn,
                         const float* __restrict__ Wsrc_nf, const float* __restrict__ a_src_nf,
                         const float* __restrict__ Wdst_nf, const float* __restrict__ a_dst_nf,
                         float* __restrict__ wav) {
    int call = blockIdx.x;
    int layer = call >> 1, which = call & 1;
    const float* Ws = which ? Wsrc_nf : Wsrc_fn;
    const float* as = which ? a_src_nf : a_src_fn;
    const float* Wd = which ? Wdst_fn : Wdst_nf;   // dst role is in the OTHER relation
    const float* ad = which ? a_dst_fn : a_dst_nf;
    Ws += layer * DIM * DIM; Wd += layer * DIM * DIM;
    as += layer * DIM; ad += layer * DIM;
    for (int it = threadIdx.x; it < 512; it += 256) {
        int k = it >> 2, h = it & 3;
        float s = 0.f, dv = 0.f;
        #pragma unroll 8
        for (int c = 0; c < 32; c++) {
            s  += Ws[k * DIM + h * 32 + c] * as[h * 32 + c];
            dv += Wd[k * DIM + h * 32 + c] * ad[h * 32 + c];
        }
        float* o = wav + (size_t)call * DIM * 8 + k * 8;
        o[h] = s; o[h + 4] = dv;
    }
}

// ---------------------------------------------------------------------------
// Transform (split-bf16 MFMA): HS(fp16) = X @ W ; [AS|AD] = X @ wav
// Block 256 (4 waves), tile 64 rows; block owns a 64-col half of W (hi/lo in
// LDS, staged once). Wave w: rows w*16..w*16+15, 4 col-tiles of 16.
// 3 MFMAs per product tile: al*bh + ah*bl + ah*bh  (~f32 accuracy).
// ---------------------------------------------------------------------------
__global__ __launch_bounds__(256, 2) void transform_kernel(
    const float* __restrict__ XA, const float* __restrict__ WA, const float* __restrict__ wavA,
    ushort* __restrict__ HSA, float* __restrict__ ASA, float* __restrict__ ADA,
    const float* __restrict__ XB, const float* __restrict__ WB, const float* __restrict__ wavB,
    ushort* __restrict__ HSB, float* __restrict__ ASB, float* __restrict__ ADB,
    int nb)
{
    int rel = (int)(blockIdx.x >= (unsigned)nb);
    const float* X  = rel ? XB : XA;
    const float* W  = rel ? WB : WA;
    const float* wav = rel ? wavB : wavA;
    ushort* HS = rel ? HSB : HSA;
    float*  AS = rel ? ASB : ASA;
    float*  AD = rel ? ADB : ADA;

    __shared__ ushort WTh[64][136], WTl[64][136];   // W^T[col][k], bf16 hi/lo
    __shared__ ushort Xh[64][136],  Xl[64][136];

    int vb = blockIdx.x - rel * nb;
    int half = vb & 1;
    int ch = half * 64;

    // stage W^T hi/lo (once per block)
    for (int i = threadIdx.x; i < 64 * DIM; i += 256) {
        int col = i & 63, k = i >> 6;
        float w = W[k * DIM + ch + col];
        ushort hi, lo; bfsplit(w, hi, lo);
        WTh[col][k] = hi; WTl[col][k] = lo;
    }

    const int wv = threadIdx.x >> 6, lane = threadIdx.x & 63;
    const int lm = lane & 15, lq = lane >> 4;
    const int r0 = wv * 16;

    for (int tile = vb >> 1; tile < NTILE; tile += (nb >> 1)) {
        int row0 = tile * 64;
        __syncthreads();
        // stage X rows hi/lo
        for (int i = threadIdx.x; i < 64 * 32; i += 256) {
            int r = i >> 5, c4 = (i & 31) * 4;
            int row = row0 + r;
            float4 v = (row < NNODE) ? ((const float4*)(X + (size_t)row * DIM))[i & 31]
                                     : make_float4(0.f, 0.f, 0.f, 0.f);
            ushort4 uh, ul;
            bfsplit(v.x, uh.x, ul.x); bfsplit(v.y, uh.y, ul.y);
            bfsplit(v.z, uh.z, ul.z); bfsplit(v.w, uh.w, ul.w);
            *(ushort4*)&Xh[r][c4] = uh;
            *(ushort4*)&Xl[r][c4] = ul;
        }
        __syncthreads();

        f32x4 acc[4] = {{0,0,0,0},{0,0,0,0},{0,0,0,0},{0,0,0,0}};
        #pragma unroll
        for (int kc = 0; kc < 4; kc++) {
            int k0 = kc * 32 + lq * 8;
            bf16x8 ah = *(const bf16x8*)&Xh[r0 + lm][k0];
            bf16x8 al = *(const bf16x8*)&Xl[r0 + lm][k0];
            #pragma unroll
            for (int ct = 0; ct < 4; ct++) {
                bf16x8 bh = *(const bf16x8*)&WTh[ct * 16 + lm][k0];
                bf16x8 bl = *(const bf16x8*)&WTl[ct * 16 + lm][k0];
                acc[ct] = __builtin_amdgcn_mfma_f32_16x16x32_bf16(al, bh, acc[ct], 0, 0, 0);
                acc[ct] = __builtin_amdgcn_mfma_f32_16x16x32_bf16(ah, bl, acc[ct], 0, 0, 0);
                acc[ct] = __builtin_amdgcn_mfma_f32_16x16x32_bf16(ah, bh, acc[ct], 0, 0, 0);
            }
        }
        // store HS as fp16; C/D layout: col = lane&15, row = lq*4 + reg
        #pragma unroll
        for (int ct = 0; ct < 4; ct++) {
            #pragma unroll
            for (int r = 0; r < 4; r++) {
                int row = row0 + r0 + lq * 4 + r;
                if (row < NNODE) HS[(size_t)row * DIM + ch + ct * 16 + lm] = f2h(acc[ct][r]);
            }
        }
        // AS/AD epilogue (half-0 blocks only): [AS|AD] = X @ wav
        if (half == 0) {
            for (int it = threadIdx.x; it < 512; it += 256) {
                int r = it >> 3, oi = it & 7;
                int row = row0 + r;
                float s = 0.f;
                #pragma unroll 4
                for (int k = 0; k < DIM; k++) {
                    float xv = bf2f(Xh[r][k]) + bf2f(Xl[r][k]);
                    s += xv * wav[k * 8 + oi];
                }
                if (row < NNODE) {
                    if (oi < 4) AS[row * 4 + oi] = s;
                    else        AD[row * 4 + (oi - 4)] = s;
                }
            }
        }
    }
}

// ---------------------------------------------------------------------------
// Aggregation: one wave per dst node, two-pass softmax, fp16 HS gathers.
// Pass 1 split 16 ways per head group; pass 2 4x unrolled independent FMAs.
// ---------------------------------------------------------------------------
__global__ __launch_bounds__(256) void agg_kernel(
    const ushort* __restrict__ HSA, const float* __restrict__ ASA,
    const float* __restrict__ ADA, const int* __restrict__ ptrA,
    const int* __restrict__ srcA, const float* __restrict__ biasA,
    float* __restrict__ outA,
    const ushort* __restrict__ HSB, const float* __restrict__ ASB,
    const float* __restrict__ ADB, const int* __restrict__ ptrB,
    const int* __restrict__ srcB, const float* __restrict__ biasB,
    float* __restrict__ outB, int nb)
{
    int rel = (int)(blockIdx.x >= (unsigned)nb);
    const ushort* HS = rel ? HSB : HSA;
    const float* AS = rel ? ASB : ASA;
    const float* AD = rel ? ADB : ADA;
    const int* ptr  = rel ? ptrB : ptrA;
    const int* srcs = rel ? srcB : srcA;
    const float* bias = rel ? biasB : biasA;
    float* out = rel ? outB : outA;

    int bid = blockIdx.x - rel * nb;
    int wave = threadIdx.x >> 6, lane = threadIdx.x & 63;
    int d = bid * 4 + wave;
    if (d >= NNODE) return;
    int hh = lane >> 4;
    float adh = AD[d * 4 + hh];
    int e0 = ptr[d], e1 = ptr[d + 1];

    // pass 1: segment max of raw AS, 16-way split within each head group
    float rm = -INFINITY;
    for (int e = e0 + (lane & 15); e < e1; e += 16)
        rm = fmaxf(rm, AS[srcs[e] * 4 + hh]);
    rm = fmaxf(rm, __shfl_xor(rm, 1));
    rm = fmaxf(rm, __shfl_xor(rm, 2));
    rm = fmaxf(rm, __shfl_xor(rm, 4));
    rm = fmaxf(rm, __shfl_xor(rm, 8));
    float araw = rm + adh;
    float m = araw > 0.f ? araw : 0.2f * araw;     // lrelu monotonic

    // pass 2: independent accumulation, 4x unrolled
    const unsigned* HSu = (const unsigned*)HS;
    float l0 = 0.f, l1 = 0.f, l2 = 0.f, l3 = 0.f;
    float ax0 = 0.f, ay0 = 0.f, ax1 = 0.f, ay1 = 0.f;
    float ax2 = 0.f, ay2 = 0.f, ax3 = 0.f, ay3 = 0.f;
    int e = e0;
    for (; e + 4 <= e1; e += 4) {
        int s0 = srcs[e], s1 = srcs[e+1], s2 = srcs[e+2], s3 = srcs[e+3];
        float v0 = AS[s0 * 4 + hh] + adh;
        float v1 = AS[s1 * 4 + hh] + adh;
        float v2 = AS[s2 * 4 + hh] + adh;
        float v3 = AS[s3 * 4 + hh] + adh;
        unsigned u0 = HSu[(size_t)s0 * 64 + lane];
        unsigned u1 = HSu[(size_t)s1 * 64 + lane];
        unsigned u2 = HSu[(size_t)s2 * 64 + lane];
        unsigned u3 = HSu[(size_t)s3 * 64 + lane];
        v0 = v0 > 0.f ? v0 : 0.2f * v0;
        v1 = v1 > 0.f ? v1 : 0.2f * v1;
        v2 = v2 > 0.f ? v2 : 0.2f * v2;
        v3 = v3 > 0.f ? v3 : 0.2f * v3;
        float p0 = __expf(v0 - m), p1 = __expf(v1 - m);
        float p2 = __expf(v2 - m), p3 = __expf(v3 - m);
        float2 h0 = up2(u0), h1 = up2(u1), h2 = up2(u2), h3 = up2(u3);
        l0 += p0; l1 += p1; l2 += p2; l3 += p3;
        ax0 += p0 * h0.x; ay0 += p0 * h0.y;
        ax1 += p1 * h1.x; ay1 += p1 * h1.y;
        ax2 += p2 * h2.x; ay2 += p2 * h2.y;
        ax3 += p3 * h3.x; ay3 += p3 * h3.y;
    }
    for (; e < e1; e++) {
        int s = srcs[e];
        float v = AS[s * 4 + hh] + adh;
        v = v > 0.f ? v : 0.2f * v;
        float p = __expf(v - m);
        float2 h = up2(HSu[(size_t)s * 64 + lane]);
        l0 += p; ax0 += p * h.x; ay0 += p * h.y;
    }
    float l = (l0 + l1) + (l2 + l3);
    float accx = (ax0 + ax1) + (ax2 + ax3);
    float accy = (ay0 + ay1) + (ay2 + ay3);

    int j0 = lane * 2;
    float inv = 1.f / (l + 1e-16f);
    float o0 = accx * inv + bias[j0];
    float o1 = accy * inv + bias[j0 + 1];
    o0 = o0 > 0.f ? o0 : expf(o0) - 1.f;           // ELU
    o1 = o1 > 0.f ? o1 : expf(o1) - 1.f;
    *(float2*)&out[(size_t)d * DIM + j0] = make_float2(o0, o1);
}

// ---------------------------------------------------------------------------
extern "C" void kernel_launch(void* const* d_in, const int* in_sizes, int n_in,
                              void* d_out, int out_size, void* d_ws, size_t ws_size,
                              hipStream_t stream) {
    const float* x_food      = (const float*)d_in[0];
    const float* x_nut       = (const float*)d_in[1];
    const float* Wsrc_fn     = (const float*)d_in[2];
    const float* Wdst_fn     = (const float*)d_in[3];
    const float* att_src_fn  = (const float*)d_in[4];
    const float* att_dst_fn  = (const float*)d_in[5];
    const float* bias_fn     = (const float*)d_in[6];
    const float* Wsrc_nf     = (const float*)d_in[7];
    const float* Wdst_nf     = (const float*)d_in[8];
    const float* att_src_nf  = (const float*)d_in[9];
    const float* att_dst_nf  = (const float*)d_in[10];
    const float* bias_nf     = (const float*)d_in[11];
    const int*   ei_fn       = (const int*)d_in[12];
    const int*   ei_nf       = (const int*)d_in[13];
    float* out = (float*)d_out;

    char* ws = (char*)d_ws;
    size_t off = 0;
    auto alloc_f = [&](size_t n) { float* p = (float*)(ws + off); off += n * 4; return p; };
    auto alloc_i = [&](size_t n) { int* p = (int*)(ws + off); off += n * 4; return p; };
    auto alloc_u = [&](size_t n) { ushort* p = (ushort*)(ws + off); off += n * 2; return p; };

    float* B_food = alloc_f((size_t)NNODE * DIM);
    float* B_nut  = alloc_f((size_t)NNODE * DIM);
    ushort* HS_fn = alloc_u((size_t)NNODE * DIM);
    ushort* HS_nf = alloc_u((size_t)NNODE * DIM);
    float* AS_fn  = alloc_f(NNODE * NHEAD);
    float* AS_nf  = alloc_f(NNODE * NHEAD);
    float* AD_fn  = alloc_f(NNODE * NHEAD);
    float* AD_nf  = alloc_f(NNODE * NHEAD);
    float* wav    = alloc_f(4 * DIM * 8);
    int* ptr_fn   = alloc_i(50004);
    int* ptr_nf   = alloc_i(50004);
    int* cur      = alloc_i(2 * NNODE);       // [fn | nf], one memset
    int* cur_fn   = cur;
    int* cur_nf   = cur + NNODE;
    int* srcs_fn  = alloc_i(NEDGE);
    int* srcs_nf  = alloc_i(NEDGE);
    int* bs       = alloc_i(512);             // [2][256]

    // ---- CSR build (fused both relations) ----
    hipMemsetAsync(cur, 0, 2 * NNODE * 4, stream);
    int eg2 = 2 * (NEDGE / 256);
    hist2<<<eg2, 256, 0, stream>>>(ei_fn + NEDGE, ei_nf + NEDGE, cur_fn, cur_nf);
    scan_partial2<<<2 * NG, 256, 0, stream>>>(cur_fn, cur_nf, bs);
    scan_top2<<<2, 256, 0, stream>>>(bs, ptr_fn, ptr_nf);
    scan_final2<<<2 * NG, 256, 0, stream>>>(bs, cur_fn, ptr_fn, cur_nf, ptr_nf);
    scatter2<<<eg2, 256, 0, stream>>>(ei_fn, ei_nf, cur_fn, cur_nf, srcs_fn, srcs_nf);

    prep_wav<<<4, 256, 0, stream>>>(Wsrc_fn, att_src_fn, Wdst_fn, att_dst_fn,
                                    Wsrc_nf, att_src_nf, Wdst_nf, att_dst_nf, wav);

    const int WL = DIM * DIM;
    const int TNB = 512;                      // transform blocks per relation
    const int ANB = (NNODE + 3) / 4;          // 12500 agg blocks per relation
    float* wav0 = wav;
    float* wav1 = wav + DIM * 8;
    float* wav2 = wav + 2 * DIM * 8;
    float* wav3 = wav + 3 * DIM * 8;

    // ---- Layer 0 ----
    transform_kernel<<<2 * TNB, 256, 0, stream>>>(
        x_food, Wsrc_fn, wav0, HS_fn, AS_fn, AD_nf,
        x_nut,  Wsrc_nf, wav1, HS_nf, AS_nf, AD_fn, TNB);
    agg_kernel<<<2 * ANB, 256, 0, stream>>>(
        HS_fn, AS_fn, AD_fn, ptr_fn, srcs_fn, bias_fn, B_nut,
        HS_nf, AS_nf, AD_nf, ptr_nf, srcs_nf, bias_nf, B_food, ANB);

    // ---- Layer 1 -> d_out ----
    transform_kernel<<<2 * TNB, 256, 0, stream>>>(
        B_food, Wsrc_fn + WL, wav2, HS_fn, AS_fn, AD_nf,
        B_nut,  Wsrc_nf + WL, wav3, HS_nf, AS_nf, AD_fn, TNB);
    agg_kernel<<<2 * ANB, 256, 0, stream>>>(
        HS_fn, AS_fn, AD_fn, ptr_fn, srcs_fn, bias_fn + DIM, out + (size_t)NNODE * DIM,
        HS_nf, AS_nf, AD_nf, ptr_nf, srcs_nf, bias_nf + DIM, out, ANB);
}

// Round 4
// 550.769 us; speedup vs baseline: 1.8977x; 1.2616x over previous
//
#include <hip/hip_runtime.h>
#include <math.h>

#define NNODE 50000
#define NEDGE 800000
#define DIM   128
#define NHEAD 4
#define NTILE ((NNODE + 63) / 64)   // 782
#define NBUCK 196                    // ceil(NNODE/256) coarse buckets (dst>>8)
#define ECHUNK 196                   // ceil(NEDGE/4096) edge chunks
#define CAP   6144                   // per-bucket LDS sort capacity (mean 4082)

typedef __bf16 bf16x8 __attribute__((ext_vector_type(8)));
typedef float  f32x4  __attribute__((ext_vector_type(4)));

static __device__ __forceinline__ void bfsplit(float x, ushort& hi, ushort& lo) {
    __bf16 h = (__bf16)x;
    float hf = (float)h;
    __bf16 l = (__bf16)(x - hf);
    hi = __builtin_bit_cast(unsigned short, h);
    lo = __builtin_bit_cast(unsigned short, l);
}
static __device__ __forceinline__ float bf2f(ushort u) {
    unsigned v = ((unsigned)u) << 16;
    return __builtin_bit_cast(float, v);
}
static __device__ __forceinline__ ushort f2h(float x) {
    _Float16 h = (_Float16)x;
    return __builtin_bit_cast(unsigned short, h);
}
static __device__ __forceinline__ float2 up2(unsigned u) {
    _Float16 a = __builtin_bit_cast(_Float16, (unsigned short)(u & 0xffff));
    _Float16 b = __builtin_bit_cast(_Float16, (unsigned short)(u >> 16));
    return make_float2((float)a, (float)b);
}

// ---------------------------------------------------------------------------
// CSR build via two-level counting sort (no random 4B global scatters).
// ---------------------------------------------------------------------------
// 1) per-chunk LDS histogram of coarse bucket (dst>>8) -> global bucket counts
__global__ __launch_bounds__(256) void bhist(const int* __restrict__ eA,
                                             const int* __restrict__ eB,
                                             int* __restrict__ bcnt) {
    int rel = (int)(blockIdx.x >= ECHUNK);
    const int* dstrow = (rel ? eB : eA) + NEDGE;
    int blk = blockIdx.x - rel * ECHUNK;
    __shared__ int hist[256];
    hist[threadIdx.x] = 0;
    __syncthreads();
    int base = blk * 4096;
    #pragma unroll
    for (int k = 0; k < 16; k++) {
        int e = base + k * 256 + threadIdx.x;
        if (e < NEDGE) atomicAdd(&hist[dstrow[e] >> 8], 1);
    }
    __syncthreads();
    int h = hist[threadIdx.x];
    if (h) atomicAdd(&bcnt[rel * 256 + threadIdx.x], h);
}

// 2) exclusive scan of bucket counts -> bko (offsets), bcur (cursors), ptr[N]
__global__ __launch_bounds__(256) void bscan(const int* __restrict__ bcnt,
                                             int* __restrict__ bko, int* __restrict__ bcur,
                                             int* __restrict__ ptrA, int* __restrict__ ptrB) {
    int rel = blockIdx.x;
    __shared__ int tmp[256];
    int t = threadIdx.x;
    int v = bcnt[rel * 256 + t];
    tmp[t] = v; __syncthreads();
    for (int off = 1; off < 256; off <<= 1) {
        int a = (t >= off) ? tmp[t - off] : 0; __syncthreads();
        tmp[t] += a; __syncthreads();
    }
    int excl = tmp[t] - v;
    bko[rel * 256 + t] = excl;
    bcur[rel * 256 + t] = excl;
    if (t == 255) (rel ? ptrB : ptrA)[NNODE] = tmp[255];
}

// 3) bucket-grouped scatter: per-(block,bucket) contiguous runs, packed u32
__global__ __launch_bounds__(256) void bscatter(const int* __restrict__ eA,
                                                const int* __restrict__ eB,
                                                int* __restrict__ bcur,
                                                unsigned* __restrict__ bktA,
                                                unsigned* __restrict__ bktB) {
    int rel = (int)(blockIdx.x >= ECHUNK);
    const int* ebase = rel ? eB : eA;
    unsigned* bkt = rel ? bktB : bktA;
    int blk = blockIdx.x - rel * ECHUNK;
    __shared__ int hist[256], bas[256], cur[256];
    hist[threadIdx.x] = 0;
    __syncthreads();
    int base = blk * 4096;
    #pragma unroll
    for (int k = 0; k < 16; k++) {
        int e = base + k * 256 + threadIdx.x;
        if (e < NEDGE) atomicAdd(&hist[ebase[NEDGE + e] >> 8], 1);
    }
    __syncthreads();
    int h = hist[threadIdx.x];
    bas[threadIdx.x] = h ? atomicAdd(&bcur[rel * 256 + threadIdx.x], h) : 0;
    cur[threadIdx.x] = 0;
    __syncthreads();
    #pragma unroll
    for (int k = 0; k < 16; k++) {
        int e = base + k * 256 + threadIdx.x;
        if (e < NEDGE) {
            int s = ebase[e], d = ebase[NEDGE + e];
            int b = d >> 8;
            int loc = atomicAdd(&cur[b], 1);
            bkt[bas[b] + loc] = ((unsigned)(d & 255) << 16) | (unsigned)s;
        }
    }
}

// 4) per-bucket exact sort in LDS -> coalesced srcs writes + ptr for free
__global__ __launch_bounds__(256) void bsort(const unsigned* __restrict__ bktA,
                                             const unsigned* __restrict__ bktB,
                                             const int* __restrict__ bko,
                                             int* __restrict__ ptrA, int* __restrict__ ptrB,
                                             int* __restrict__ srcA, int* __restrict__ srcB) {
    int rel = (int)(blockIdx.x >= NBUCK);
    const unsigned* bkt = rel ? bktB : bktA;
    int* ptr  = rel ? ptrB : ptrA;
    int* srcs = rel ? srcB : srcA;
    int b = blockIdx.x - rel * NBUCK;
    int beg = bko[rel * 256 + b], end = bko[rel * 256 + b + 1];
    int cnt_e = end - beg;
    __shared__ int hist[256], excl[256], cur[256];
    __shared__ unsigned sorted[CAP];
    int t = threadIdx.x;
    hist[t] = 0;
    __syncthreads();
    for (int i = t; i < cnt_e; i += 256) atomicAdd(&hist[bkt[beg + i] >> 16], 1);
    __syncthreads();
    int v = hist[t];
    excl[t] = v; __syncthreads();
    for (int off = 1; off < 256; off <<= 1) {
        int a = (t >= off) ? excl[t - off] : 0; __syncthreads();
        excl[t] += a; __syncthreads();
    }
    int ex = excl[t] - v;
    int d = b * 256 + t;
    if (d < NNODE) ptr[d] = beg + ex;
    cur[t] = ex;
    __syncthreads();
    for (int i = t; i < cnt_e; i += 256) {
        unsigned u = bkt[beg + i];
        int dl = u >> 16;
        int p = atomicAdd(&cur[dl], 1);
        if (p < CAP) sorted[p] = u & 0xffffu;
        else         srcs[beg + p] = (int)(u & 0xffffu);   // overflow fallback
    }
    __syncthreads();
    int lim = cnt_e < CAP ? cnt_e : CAP;
    for (int i = t; i < lim; i += 256) srcs[beg + i] = (int)sorted[i];
}

// ---------------------------------------------------------------------------
// wav[call][k][8]: cols 0..3 = was (Wsrc·a_src), 4..7 = wad (Wdst·a_dst)
// ---------------------------------------------------------------------------
__global__ void prep_wav(const float* __restrict__ Wsrc_fn, const float* __restrict__ a_src_fn,
                         const float* __restrict__ Wdst_fn, const float* __restrict__ a_dst_fn,
                         const float* __restrict__ Wsrc_nf, const float* __restrict__ a_src_nf,
                         const float* __restrict__ Wdst_nf, const float* __restrict__ a_dst_nf,
                         float* __restrict__ wav) {
    int call = blockIdx.x;
    int layer = call >> 1, which = call & 1;
    const float* Ws = which ? Wsrc_nf : Wsrc_fn;
    const float* as = which ? a_src_nf : a_src_fn;
    const float* Wd = which ? Wdst_fn : Wdst_nf;
    const float* ad = which ? a_dst_fn : a_dst_nf;
    Ws += layer * DIM * DIM; Wd += layer * DIM * DIM;
    as += layer * DIM; ad += layer * DIM;
    for (int it = threadIdx.x; it < 512; it += 256) {
        int k = it >> 2, h = it & 3;
        float s = 0.f, dv = 0.f;
        #pragma unroll 8
        for (int c = 0; c < 32; c++) {
            s  += Ws[k * DIM + h * 32 + c] * as[h * 32 + c];
            dv += Wd[k * DIM + h * 32 + c] * ad[h * 32 + c];
        }
        float* o = wav + (size_t)call * DIM * 8 + k * 8;
        o[h] = s; o[h + 4] = dv;
    }
}

// ---------------------------------------------------------------------------
// Transform (split-bf16 MFMA): HS(fp16) = X @ W ; [AS|AD] = X @ wav
// ---------------------------------------------------------------------------
__global__ __launch_bounds__(256, 2) void transform_kernel(
    const float* __restrict__ XA, const float* __restrict__ WA, const float* __restrict__ wavA,
    ushort* __restrict__ HSA, float* __restrict__ ASA, float* __restrict__ ADA,
    const float* __restrict__ XB, const float* __restrict__ WB, const float* __restrict__ wavB,
    ushort* __restrict__ HSB, float* __restrict__ ASB, float* __restrict__ ADB,
    int nb)
{
    int rel = (int)(blockIdx.x >= (unsigned)nb);
    const float* X  = rel ? XB : XA;
    const float* W  = rel ? WB : WA;
    const float* wav = rel ? wavB : wavA;
    ushort* HS = rel ? HSB : HSA;
    float*  AS = rel ? ASB : ASA;
    float*  AD = rel ? ADB : ADA;

    __shared__ ushort WTh[64][136], WTl[64][136];
    __shared__ ushort Xh[64][136],  Xl[64][136];

    int vb = blockIdx.x - rel * nb;
    int half = vb & 1;
    int ch = half * 64;

    for (int i = threadIdx.x; i < 64 * DIM; i += 256) {
        int col = i & 63, k = i >> 6;
        float w = W[k * DIM + ch + col];
        ushort hi, lo; bfsplit(w, hi, lo);
        WTh[col][k] = hi; WTl[col][k] = lo;
    }

    const int wv = threadIdx.x >> 6, lane = threadIdx.x & 63;
    const int lm = lane & 15, lq = lane >> 4;
    const int r0 = wv * 16;

    for (int tile = vb >> 1; tile < NTILE; tile += (nb >> 1)) {
        int row0 = tile * 64;
        __syncthreads();
        for (int i = threadIdx.x; i < 64 * 32; i += 256) {
            int r = i >> 5, c4 = (i & 31) * 4;
            int row = row0 + r;
            float4 v = (row < NNODE) ? ((const float4*)(X + (size_t)row * DIM))[i & 31]
                                     : make_float4(0.f, 0.f, 0.f, 0.f);
            ushort4 uh, ul;
            bfsplit(v.x, uh.x, ul.x); bfsplit(v.y, uh.y, ul.y);
            bfsplit(v.z, uh.z, ul.z); bfsplit(v.w, uh.w, ul.w);
            *(ushort4*)&Xh[r][c4] = uh;
            *(ushort4*)&Xl[r][c4] = ul;
        }
        __syncthreads();

        f32x4 acc[4] = {{0,0,0,0},{0,0,0,0},{0,0,0,0},{0,0,0,0}};
        #pragma unroll
        for (int kc = 0; kc < 4; kc++) {
            int k0 = kc * 32 + lq * 8;
            bf16x8 ah = *(const bf16x8*)&Xh[r0 + lm][k0];
            bf16x8 al = *(const bf16x8*)&Xl[r0 + lm][k0];
            #pragma unroll
            for (int ct = 0; ct < 4; ct++) {
                bf16x8 bh = *(const bf16x8*)&WTh[ct * 16 + lm][k0];
                bf16x8 bl = *(const bf16x8*)&WTl[ct * 16 + lm][k0];
                acc[ct] = __builtin_amdgcn_mfma_f32_16x16x32_bf16(al, bh, acc[ct], 0, 0, 0);
                acc[ct] = __builtin_amdgcn_mfma_f32_16x16x32_bf16(ah, bl, acc[ct], 0, 0, 0);
                acc[ct] = __builtin_amdgcn_mfma_f32_16x16x32_bf16(ah, bh, acc[ct], 0, 0, 0);
            }
        }
        #pragma unroll
        for (int ct = 0; ct < 4; ct++) {
            #pragma unroll
            for (int r = 0; r < 4; r++) {
                int row = row0 + r0 + lq * 4 + r;
                if (row < NNODE) HS[(size_t)row * DIM + ch + ct * 16 + lm] = f2h(acc[ct][r]);
            }
        }
        if (half == 0) {
            for (int it = threadIdx.x; it < 512; it += 256) {
                int r = it >> 3, oi = it & 7;
                int row = row0 + r;
                float s = 0.f;
                #pragma unroll 4
                for (int k = 0; k < DIM; k++) {
                    float xv = bf2f(Xh[r][k]) + bf2f(Xl[r][k]);
                    s += xv * wav[k * 8 + oi];
                }
                if (row < NNODE) {
                    if (oi < 4) AS[row * 4 + oi] = s;
                    else        AD[row * 4 + (oi - 4)] = s;
                }
            }
        }
    }
}

// ---------------------------------------------------------------------------
// Aggregation: one wave per dst node, two-pass softmax, fp16 HS gathers.
// ---------------------------------------------------------------------------
__global__ __launch_bounds__(256) void agg_kernel(
    const ushort* __restrict__ HSA, const float* __restrict__ ASA,
    const float* __restrict__ ADA, const int* __restrict__ ptrA,
    const int* __restrict__ srcA, const float* __restrict__ biasA,
    float* __restrict__ outA,
    const ushort* __restrict__ HSB, const float* __restrict__ ASB,
    const float* __restrict__ ADB, const int* __restrict__ ptrB,
    const int* __restrict__ srcB, const float* __restrict__ biasB,
    float* __restrict__ outB, int nb)
{
    int rel = (int)(blockIdx.x >= (unsigned)nb);
    const ushort* HS = rel ? HSB : HSA;
    const float* AS = rel ? ASB : ASA;
    const float* AD = rel ? ADB : ADA;
    const int* ptr  = rel ? ptrB : ptrA;
    const int* srcs = rel ? srcB : srcA;
    const float* bias = rel ? biasB : biasA;
    float* out = rel ? outB : outA;

    int bid = blockIdx.x - rel * nb;
    int wave = threadIdx.x >> 6, lane = threadIdx.x & 63;
    int d = bid * 4 + wave;
    if (d >= NNODE) return;
    int hh = lane >> 4;
    float adh = AD[d * 4 + hh];
    int e0 = ptr[d], e1 = ptr[d + 1];

    float rm = -INFINITY;
    for (int e = e0 + (lane & 15); e < e1; e += 16)
        rm = fmaxf(rm, AS[srcs[e] * 4 + hh]);
    rm = fmaxf(rm, __shfl_xor(rm, 1));
    rm = fmaxf(rm, __shfl_xor(rm, 2));
    rm = fmaxf(rm, __shfl_xor(rm, 4));
    rm = fmaxf(rm, __shfl_xor(rm, 8));
    float araw = rm + adh;
    float m = araw > 0.f ? araw : 0.2f * araw;

    const unsigned* HSu = (const unsigned*)HS;
    float l0 = 0.f, l1 = 0.f, l2 = 0.f, l3 = 0.f;
    float ax0 = 0.f, ay0 = 0.f, ax1 = 0.f, ay1 = 0.f;
    float ax2 = 0.f, ay2 = 0.f, ax3 = 0.f, ay3 = 0.f;
    int e = e0;
    for (; e + 4 <= e1; e += 4) {
        int s0 = srcs[e], s1 = srcs[e+1], s2 = srcs[e+2], s3 = srcs[e+3];
        float v0 = AS[s0 * 4 + hh] + adh;
        float v1 = AS[s1 * 4 + hh] + adh;
        float v2 = AS[s2 * 4 + hh] + adh;
        float v3 = AS[s3 * 4 + hh] + adh;
        unsigned u0 = HSu[(size_t)s0 * 64 + lane];
        unsigned u1 = HSu[(size_t)s1 * 64 + lane];
        unsigned u2 = HSu[(size_t)s2 * 64 + lane];
        unsigned u3 = HSu[(size_t)s3 * 64 + lane];
        v0 = v0 > 0.f ? v0 : 0.2f * v0;
        v1 = v1 > 0.f ? v1 : 0.2f * v1;
        v2 = v2 > 0.f ? v2 : 0.2f * v2;
        v3 = v3 > 0.f ? v3 : 0.2f * v3;
        float p0 = __expf(v0 - m), p1 = __expf(v1 - m);
        float p2 = __expf(v2 - m), p3 = __expf(v3 - m);
        float2 h0 = up2(u0), h1 = up2(u1), h2 = up2(u2), h3 = up2(u3);
        l0 += p0; l1 += p1; l2 += p2; l3 += p3;
        ax0 += p0 * h0.x; ay0 += p0 * h0.y;
        ax1 += p1 * h1.x; ay1 += p1 * h1.y;
        ax2 += p2 * h2.x; ay2 += p2 * h2.y;
        ax3 += p3 * h3.x; ay3 += p3 * h3.y;
    }
    for (; e < e1; e++) {
        int s = srcs[e];
        float v = AS[s * 4 + hh] + adh;
        v = v > 0.f ? v : 0.2f * v;
        float p = __expf(v - m);
        float2 h = up2(HSu[(size_t)s * 64 + lane]);
        l0 += p; ax0 += p * h.x; ay0 += p * h.y;
    }
    float l = (l0 + l1) + (l2 + l3);
    float accx = (ax0 + ax1) + (ax2 + ax3);
    float accy = (ay0 + ay1) + (ay2 + ay3);

    int j0 = lane * 2;
    float inv = 1.f / (l + 1e-16f);
    float o0 = accx * inv + bias[j0];
    float o1 = accy * inv + bias[j0 + 1];
    o0 = o0 > 0.f ? o0 : expf(o0) - 1.f;
    o1 = o1 > 0.f ? o1 : expf(o1) - 1.f;
    *(float2*)&out[(size_t)d * DIM + j0] = make_float2(o0, o1);
}

// ---------------------------------------------------------------------------
extern "C" void kernel_launch(void* const* d_in, const int* in_sizes, int n_in,
                              void* d_out, int out_size, void* d_ws, size_t ws_size,
                              hipStream_t stream) {
    const float* x_food      = (const float*)d_in[0];
    const float* x_nut       = (const float*)d_in[1];
    const float* Wsrc_fn     = (const float*)d_in[2];
    const float* Wdst_fn     = (const float*)d_in[3];
    const float* att_src_fn  = (const float*)d_in[4];
    const float* att_dst_fn  = (const float*)d_in[5];
    const float* bias_fn     = (const float*)d_in[6];
    const float* Wsrc_nf     = (const float*)d_in[7];
    const float* Wdst_nf     = (const float*)d_in[8];
    const float* att_src_nf  = (const float*)d_in[9];
    const float* att_dst_nf  = (const float*)d_in[10];
    const float* bias_nf     = (const float*)d_in[11];
    const int*   ei_fn       = (const int*)d_in[12];
    const int*   ei_nf       = (const int*)d_in[13];
    float* out = (float*)d_out;

    char* ws = (char*)d_ws;
    size_t off = 0;
    auto alloc_f = [&](size_t n) { float* p = (float*)(ws + off); off += n * 4; return p; };
    auto alloc_i = [&](size_t n) { int* p = (int*)(ws + off); off += n * 4; return p; };
    auto alloc_u = [&](size_t n) { ushort* p = (ushort*)(ws + off); off += n * 2; return p; };

    float* B_food = alloc_f((size_t)NNODE * DIM);
    float* B_nut  = alloc_f((size_t)NNODE * DIM);
    ushort* HS_fn = alloc_u((size_t)NNODE * DIM);
    ushort* HS_nf = alloc_u((size_t)NNODE * DIM);
    float* AS_fn  = alloc_f(NNODE * NHEAD);
    float* AS_nf  = alloc_f(NNODE * NHEAD);
    float* AD_fn  = alloc_f(NNODE * NHEAD);
    float* AD_nf  = alloc_f(NNODE * NHEAD);
    float* wav    = alloc_f(4 * DIM * 8);
    int* ptr_fn   = alloc_i(50004);
    int* ptr_nf   = alloc_i(50004);
    int* srcs_fn  = alloc_i(NEDGE);
    int* srcs_nf  = alloc_i(NEDGE);
    int* bcnt     = alloc_i(512);
    int* bko      = alloc_i(512);
    int* bcur     = alloc_i(512);
    // bkt buffers alias B_food/B_nut (dead until after CSR build)
    unsigned* bkt_fn = (unsigned*)B_food;
    unsigned* bkt_nf = (unsigned*)B_nut;

    // ---- CSR build: two-level counting sort ----
    hipMemsetAsync(bcnt, 0, 512 * 4, stream);
    bhist<<<2 * ECHUNK, 256, 0, stream>>>(ei_fn, ei_nf, bcnt);
    bscan<<<2, 256, 0, stream>>>(bcnt, bko, bcur, ptr_fn, ptr_nf);
    bscatter<<<2 * ECHUNK, 256, 0, stream>>>(ei_fn, ei_nf, bcur, bkt_fn, bkt_nf);
    bsort<<<2 * NBUCK, 256, 0, stream>>>(bkt_fn, bkt_nf, bko, ptr_fn, ptr_nf, srcs_fn, srcs_nf);

    prep_wav<<<4, 256, 0, stream>>>(Wsrc_fn, att_src_fn, Wdst_fn, att_dst_fn,
                                    Wsrc_nf, att_src_nf, Wdst_nf, att_dst_nf, wav);

    const int WL = DIM * DIM;
    const int TNB = 512;
    const int ANB = (NNODE + 3) / 4;
    float* wav0 = wav;
    float* wav1 = wav + DIM * 8;
    float* wav2 = wav + 2 * DIM * 8;
    float* wav3 = wav + 3 * DIM * 8;

    // ---- Layer 0 ----
    transform_kernel<<<2 * TNB, 256, 0, stream>>>(
        x_food, Wsrc_fn, wav0, HS_fn, AS_fn, AD_nf,
        x_nut,  Wsrc_nf, wav1, HS_nf, AS_nf, AD_fn, TNB);
    agg_kernel<<<2 * ANB, 256, 0, stream>>>(
        HS_fn, AS_fn, AD_fn, ptr_fn, srcs_fn, bias_fn, B_nut,
        HS_nf, AS_nf, AD_nf, ptr_nf, srcs_nf, bias_nf, B_food, ANB);

    // ---- Layer 1 -> d_out ----
    transform_kernel<<<2 * TNB, 256, 0, stream>>>(
        B_food, Wsrc_fn + WL, wav2, HS_fn, AS_fn, AD_nf,
        B_nut,  Wsrc_nf + WL, wav3, HS_nf, AS_nf, AD_fn, TNB);
    agg_kernel<<<2 * ANB, 256, 0, stream>>>(
        HS_fn, AS_fn, AD_fn, ptr_fn, srcs_fn, bias_fn + DIM, out + (size_t)NNODE * DIM,
        HS_nf, AS_nf, AD_nf, ptr_nf, srcs_nf, bias_nf + DIM, out, ANB);
}

// Round 5
// 493.794 us; speedup vs baseline: 2.1167x; 1.1154x over previous
//
#include <hip/hip_runtime.h>
#include <math.h>

#define NNODE 50000
#define NEDGE 800000
#define DIM   128
#define NHEAD 4
#define NTILE ((NNODE + 63) / 64)   // 782
#define NBUCK 196                    // ceil(NNODE/256) coarse buckets (dst>>8)
#define ECHUNK 196                   // ceil(NEDGE/4096) edge chunks
#define CAP   6144                   // per-bucket LDS sort capacity (mean 4082)
#define EB    (NEDGE / 256)          // 3125 edge blocks per relation

typedef __bf16 bf16x8 __attribute__((ext_vector_type(8)));
typedef float  f32x4  __attribute__((ext_vector_type(4)));
typedef float  f32x2  __attribute__((ext_vector_type(2)));

static __device__ __forceinline__ void bfsplit(float x, ushort& hi, ushort& lo) {
    __bf16 h = (__bf16)x;
    float hf = (float)h;
    __bf16 l = (__bf16)(x - hf);
    hi = __builtin_bit_cast(unsigned short, h);
    lo = __builtin_bit_cast(unsigned short, l);
}
static __device__ __forceinline__ float bf2f(ushort u) {
    unsigned v = ((unsigned)u) << 16;
    return __builtin_bit_cast(float, v);
}
static __device__ __forceinline__ ushort f2h(float x) {
    _Float16 h = (_Float16)x;
    return __builtin_bit_cast(unsigned short, h);
}
static __device__ __forceinline__ f32x2 up2v(unsigned u) {
    f32x2 r;
    r.x = (float)__builtin_bit_cast(_Float16, (unsigned short)(u & 0xffff));
    r.y = (float)__builtin_bit_cast(_Float16, (unsigned short)(u >> 16));
    return r;
}
// monotone float<->uint encoding for atomicMax on floats
static __device__ __forceinline__ unsigned encf(float f) {
    unsigned u = __builtin_bit_cast(unsigned, f);
    return (u >> 31) ? ~u : (u | 0x80000000u);
}
static __device__ __forceinline__ float decf(unsigned x) {
    unsigned u = (x >> 31) ? (x & 0x7fffffffu) : ~x;
    return __builtin_bit_cast(float, u);
}

// ---------------------------------------------------------------------------
// CSR build via two-level counting sort (no random 4B global scatters).
// ---------------------------------------------------------------------------
__global__ __launch_bounds__(256) void bhist(const int* __restrict__ eA,
                                             const int* __restrict__ eB,
                                             int* __restrict__ bcnt) {
    int rel = (int)(blockIdx.x >= ECHUNK);
    const int* dstrow = (rel ? eB : eA) + NEDGE;
    int blk = blockIdx.x - rel * ECHUNK;
    __shared__ int hist[256];
    hist[threadIdx.x] = 0;
    __syncthreads();
    int base = blk * 4096;
    #pragma unroll
    for (int k = 0; k < 16; k++) {
        int e = base + k * 256 + threadIdx.x;
        if (e < NEDGE) atomicAdd(&hist[dstrow[e] >> 8], 1);
    }
    __syncthreads();
    int h = hist[threadIdx.x];
    if (h) atomicAdd(&bcnt[rel * 256 + threadIdx.x], h);
}

__global__ __launch_bounds__(256) void bscan(const int* __restrict__ bcnt,
                                             int* __restrict__ bko, int* __restrict__ bcur,
                                             int* __restrict__ ptrA, int* __restrict__ ptrB) {
    int rel = blockIdx.x;
    __shared__ int tmp[256];
    int t = threadIdx.x;
    int v = bcnt[rel * 256 + t];
    tmp[t] = v; __syncthreads();
    for (int off = 1; off < 256; off <<= 1) {
        int a = (t >= off) ? tmp[t - off] : 0; __syncthreads();
        tmp[t] += a; __syncthreads();
    }
    int excl = tmp[t] - v;
    bko[rel * 256 + t] = excl;
    bcur[rel * 256 + t] = excl;
    if (t == 255) (rel ? ptrB : ptrA)[NNODE] = tmp[255];
}

__global__ __launch_bounds__(256) void bscatter(const int* __restrict__ eA,
                                                const int* __restrict__ eB,
                                                int* __restrict__ bcur,
                                                unsigned* __restrict__ bktA,
                                                unsigned* __restrict__ bktB) {
    int rel = (int)(blockIdx.x >= ECHUNK);
    const int* ebase = rel ? eB : eA;
    unsigned* bkt = rel ? bktB : bktA;
    int blk = blockIdx.x - rel * ECHUNK;
    __shared__ int hist[256], bas[256], cur[256];
    hist[threadIdx.x] = 0;
    __syncthreads();
    int base = blk * 4096;
    #pragma unroll
    for (int k = 0; k < 16; k++) {
        int e = base + k * 256 + threadIdx.x;
        if (e < NEDGE) atomicAdd(&hist[ebase[NEDGE + e] >> 8], 1);
    }
    __syncthreads();
    int h = hist[threadIdx.x];
    bas[threadIdx.x] = h ? atomicAdd(&bcur[rel * 256 + threadIdx.x], h) : 0;
    cur[threadIdx.x] = 0;
    __syncthreads();
    #pragma unroll
    for (int k = 0; k < 16; k++) {
        int e = base + k * 256 + threadIdx.x;
        if (e < NEDGE) {
            int s = ebase[e], d = ebase[NEDGE + e];
            int b = d >> 8;
            int loc = atomicAdd(&cur[b], 1);
            bkt[bas[b] + loc] = ((unsigned)(d & 255) << 16) | (unsigned)s;
        }
    }
}

// per-bucket exact sort in LDS -> coalesced srcs/dsts (ushort) + ptr for free
__global__ __launch_bounds__(256) void bsort(const unsigned* __restrict__ bktA,
                                             const unsigned* __restrict__ bktB,
                                             const int* __restrict__ bko,
                                             int* __restrict__ ptrA, int* __restrict__ ptrB,
                                             ushort* __restrict__ srcA, ushort* __restrict__ srcB,
                                             ushort* __restrict__ dstA, ushort* __restrict__ dstB) {
    int rel = (int)(blockIdx.x >= NBUCK);
    const unsigned* bkt = rel ? bktB : bktA;
    int* ptr   = rel ? ptrB : ptrA;
    ushort* srcs = rel ? srcB : srcA;
    ushort* dsts = rel ? dstB : dstA;
    int b = blockIdx.x - rel * NBUCK;
    int beg = bko[rel * 256 + b], end = bko[rel * 256 + b + 1];
    int cnt_e = end - beg;
    __shared__ int hist[256], excl[256], cur[256];
    __shared__ unsigned sorted[CAP];
    int t = threadIdx.x;
    hist[t] = 0;
    __syncthreads();
    for (int i = t; i < cnt_e; i += 256) atomicAdd(&hist[bkt[beg + i] >> 16], 1);
    __syncthreads();
    int v = hist[t];
    excl[t] = v; __syncthreads();
    for (int off = 1; off < 256; off <<= 1) {
        int a = (t >= off) ? excl[t - off] : 0; __syncthreads();
        excl[t] += a; __syncthreads();
    }
    int ex = excl[t] - v;
    int d = b * 256 + t;
    if (d < NNODE) ptr[d] = beg + ex;
    cur[t] = ex;
    __syncthreads();
    for (int i = t; i < cnt_e; i += 256) {
        unsigned u = bkt[beg + i];
        int dl = u >> 16;
        int p = atomicAdd(&cur[dl], 1);
        if (p < CAP) sorted[p] = u;
        else {  // statistically unreachable overflow fallback
            srcs[beg + p] = (ushort)(u & 0xffffu);
            dsts[beg + p] = (ushort)(b * 256 + dl);
        }
    }
    __syncthreads();
    int lim = cnt_e < CAP ? cnt_e : CAP;
    for (int i = t; i < lim; i += 256) {
        unsigned u = sorted[i];
        srcs[beg + i] = (ushort)(u & 0xffffu);
        dsts[beg + i] = (ushort)(b * 256 + (u >> 16));
    }
}

// ---------------------------------------------------------------------------
// wav[call][k][8]: cols 0..3 = was (Wsrc·a_src), 4..7 = wad (Wdst·a_dst)
// ---------------------------------------------------------------------------
__global__ void prep_wav(const float* __restrict__ Wsrc_fn, const float* __restrict__ a_src_fn,
                         const float* __restrict__ Wdst_fn, const float* __restrict__ a_dst_fn,
                         const float* __restrict__ Wsrc_nf, const float* __restrict__ a_src_nf,
                         const float* __restrict__ Wdst_nf, const float* __restrict__ a_dst_nf,
                         float* __restrict__ wav) {
    int call = blockIdx.x;
    int layer = call >> 1, which = call & 1;
    const float* Ws = which ? Wsrc_nf : Wsrc_fn;
    const float* as = which ? a_src_nf : a_src_fn;
    const float* Wd = which ? Wdst_fn : Wdst_nf;
    const float* ad = which ? a_dst_fn : a_dst_nf;
    Ws += layer * DIM * DIM; Wd += layer * DIM * DIM;
    as += layer * DIM; ad += layer * DIM;
    for (int it = threadIdx.x; it < 512; it += 256) {
        int k = it >> 2, h = it & 3;
        float s = 0.f, dv = 0.f;
        #pragma unroll 8
        for (int c = 0; c < 32; c++) {
            s  += Ws[k * DIM + h * 32 + c] * as[h * 32 + c];
            dv += Wd[k * DIM + h * 32 + c] * ad[h * 32 + c];
        }
        float* o = wav + (size_t)call * DIM * 8 + k * 8;
        o[h] = s; o[h + 4] = dv;
    }
}

// ---------------------------------------------------------------------------
// Transform (split-bf16 MFMA): HS(fp16) = X @ W ; [AS|AD] = X @ wav
// Also reduces per-head global max of AS into Mg (encoded uint, atomicMax).
// ---------------------------------------------------------------------------
__global__ __launch_bounds__(256, 2) void transform_kernel(
    const float* __restrict__ XA, const float* __restrict__ WA, const float* __restrict__ wavA,
    ushort* __restrict__ HSA, float* __restrict__ ASA, float* __restrict__ ADA,
    const float* __restrict__ XB, const float* __restrict__ WB, const float* __restrict__ wavB,
    ushort* __restrict__ HSB, float* __restrict__ ASB, float* __restrict__ ADB,
    unsigned* __restrict__ Mg, int nb)
{
    int rel = (int)(blockIdx.x >= (unsigned)nb);
    const float* X  = rel ? XB : XA;
    const float* W  = rel ? WB : WA;
    const float* wav = rel ? wavB : wavA;
    ushort* HS = rel ? HSB : HSA;
    float*  AS = rel ? ASB : ASA;
    float*  AD = rel ? ADB : ADA;

    __shared__ ushort WTh[64][136], WTl[64][136];
    __shared__ ushort Xh[64][136],  Xl[64][136];
    __shared__ float  wavs[DIM * 8];
    __shared__ unsigned mloc[4];

    int vb = blockIdx.x - rel * nb;
    int half = vb & 1;
    int ch = half * 64;

    for (int i = threadIdx.x; i < 64 * DIM; i += 256) {
        int col = i & 63, k = i >> 6;
        float w = W[k * DIM + ch + col];
        ushort hi, lo; bfsplit(w, hi, lo);
        WTh[col][k] = hi; WTl[col][k] = lo;
    }
    for (int i = threadIdx.x; i < DIM * 8; i += 256) wavs[i] = wav[i];
    if (threadIdx.x < 4) mloc[threadIdx.x] = 0;

    const int wv = threadIdx.x >> 6, lane = threadIdx.x & 63;
    const int lm = lane & 15, lq = lane >> 4;
    const int r0 = wv * 16;

    for (int tile = vb >> 1; tile < NTILE; tile += (nb >> 1)) {
        int row0 = tile * 64;
        __syncthreads();
        for (int i = threadIdx.x; i < 64 * 32; i += 256) {
            int r = i >> 5, c4 = (i & 31) * 4;
            int row = row0 + r;
            float4 v = (row < NNODE) ? ((const float4*)(X + (size_t)row * DIM))[i & 31]
                                     : make_float4(0.f, 0.f, 0.f, 0.f);
            ushort4 uh, ul;
            bfsplit(v.x, uh.x, ul.x); bfsplit(v.y, uh.y, ul.y);
            bfsplit(v.z, uh.z, ul.z); bfsplit(v.w, uh.w, ul.w);
            *(ushort4*)&Xh[r][c4] = uh;
            *(ushort4*)&Xl[r][c4] = ul;
        }
        __syncthreads();

        f32x4 acc[4] = {{0,0,0,0},{0,0,0,0},{0,0,0,0},{0,0,0,0}};
        #pragma unroll
        for (int kc = 0; kc < 4; kc++) {
            int k0 = kc * 32 + lq * 8;
            bf16x8 ah = *(const bf16x8*)&Xh[r0 + lm][k0];
            bf16x8 al = *(const bf16x8*)&Xl[r0 + lm][k0];
            #pragma unroll
            for (int ct = 0; ct < 4; ct++) {
                bf16x8 bh = *(const bf16x8*)&WTh[ct * 16 + lm][k0];
                bf16x8 bl = *(const bf16x8*)&WTl[ct * 16 + lm][k0];
                acc[ct] = __builtin_amdgcn_mfma_f32_16x16x32_bf16(al, bh, acc[ct], 0, 0, 0);
                acc[ct] = __builtin_amdgcn_mfma_f32_16x16x32_bf16(ah, bl, acc[ct], 0, 0, 0);
                acc[ct] = __builtin_amdgcn_mfma_f32_16x16x32_bf16(ah, bh, acc[ct], 0, 0, 0);
            }
        }
        #pragma unroll
        for (int ct = 0; ct < 4; ct++) {
            #pragma unroll
            for (int r = 0; r < 4; r++) {
                int row = row0 + r0 + lq * 4 + r;
                if (row < NNODE) HS[(size_t)row * DIM + ch + ct * 16 + lm] = f2h(acc[ct][r]);
            }
        }
        if (half == 0) {
            for (int it = threadIdx.x; it < 512; it += 256) {
                int r = it >> 3, oi = it & 7;
                int row = row0 + r;
                float s = 0.f;
                #pragma unroll 4
                for (int k = 0; k < DIM; k++) {
                    float xv = bf2f(Xh[r][k]) + bf2f(Xl[r][k]);
                    s += xv * wavs[k * 8 + oi];
                }
                if (row < NNODE) {
                    if (oi < 4) { AS[row * 4 + oi] = s; atomicMax(&mloc[oi], encf(s)); }
                    else        AD[row * 4 + (oi - 4)] = s;
                }
            }
        }
    }
    __syncthreads();
    if (half == 0 && threadIdx.x < 4)
        atomicMax(&Mg[rel * 4 + threadIdx.x], mloc[threadIdx.x]);
}

// ---------------------------------------------------------------------------
// Edge-parallel alpha: alpha[h][e] = exp(lrelu(AS[s,h]+AD[d,h]) - m_{d,h}),
// m_{d,h} = lrelu(maxAS_h + AD[d,h]) >= segment max (softmax shift-invariant).
// ---------------------------------------------------------------------------
__global__ __launch_bounds__(256) void edge_alpha(
    const ushort* __restrict__ srcA, const ushort* __restrict__ dstA,
    const float* __restrict__ ASA, const float* __restrict__ ADA,
    _Float16* __restrict__ alA,
    const ushort* __restrict__ srcB, const ushort* __restrict__ dstB,
    const float* __restrict__ ASB, const float* __restrict__ ADB,
    _Float16* __restrict__ alB,
    const unsigned* __restrict__ Mg)
{
    int rel = (int)(blockIdx.x >= EB);
    const ushort* srcs = rel ? srcB : srcA;
    const ushort* dsts = rel ? dstB : dstA;
    const float* AS = rel ? ASB : ASA;
    const float* AD = rel ? ADB : ADA;
    _Float16* al = rel ? alB : alA;
    int e = (blockIdx.x - rel * EB) * 256 + threadIdx.x;
    int s = srcs[e], d = dsts[e];
    f32x4 as4 = ((const f32x4*)AS)[s];
    f32x4 ad4 = ((const f32x4*)AD)[d];
    #pragma unroll
    for (int h = 0; h < 4; h++) {
        float mx = decf(Mg[rel * 4 + h]);
        float v = as4[h] + ad4[h];
        v = v > 0.f ? v : 0.2f * v;
        float mm = mx + ad4[h];
        mm = mm > 0.f ? mm : 0.2f * mm;
        al[h * NEDGE + e] = (_Float16)__expf(v - mm);
    }
}

// ---------------------------------------------------------------------------
// Aggregation: one wave per dst node; sequential alpha + srcs, HS gather,
// packed f32x2 FMA. No softmax math in the loop. Fuses bias + ELU.
// ---------------------------------------------------------------------------
__global__ __launch_bounds__(256) void agg_kernel(
    const ushort* __restrict__ HSA, const _Float16* __restrict__ alA,
    const int* __restrict__ ptrA, const ushort* __restrict__ srcA,
    const float* __restrict__ biasA, float* __restrict__ outA,
    const ushort* __restrict__ HSB, const _Float16* __restrict__ alB,
    const int* __restrict__ ptrB, const ushort* __restrict__ srcB,
    const float* __restrict__ biasB, float* __restrict__ outB, int nb)
{
    int rel = (int)(blockIdx.x >= (unsigned)nb);
    const unsigned* HSu = (const unsigned*)(rel ? HSB : HSA);
    const ushort* srcs = rel ? srcB : srcA;
    const int* ptr = rel ? ptrB : ptrA;
    const float* bias = rel ? biasB : biasA;
    float* out = rel ? outB : outA;

    int bid = blockIdx.x - rel * nb;
    int wave = threadIdx.x >> 6, lane = threadIdx.x & 63;
    int d = bid * 4 + wave;
    if (d >= NNODE) return;
    int hh = lane >> 4;
    const _Float16* aH = (rel ? alB : alA) + hh * NEDGE;
    int e0 = ptr[d], e1 = ptr[d + 1];

    f32x2 acc0 = {0.f, 0.f}, acc1 = acc0, acc2 = acc0, acc3 = acc0;
    float l0 = 0.f, l1 = 0.f, l2 = 0.f, l3 = 0.f;
    int e = e0;
    for (; e + 4 <= e1; e += 4) {
        int s0 = srcs[e], s1 = srcs[e + 1], s2 = srcs[e + 2], s3 = srcs[e + 3];
        float a0 = (float)aH[e], a1 = (float)aH[e + 1];
        float a2 = (float)aH[e + 2], a3 = (float)aH[e + 3];
        unsigned u0 = HSu[(s0 << 6) + lane];
        unsigned u1 = HSu[(s1 << 6) + lane];
        unsigned u2 = HSu[(s2 << 6) + lane];
        unsigned u3 = HSu[(s3 << 6) + lane];
        f32x2 h0 = up2v(u0), h1 = up2v(u1), h2 = up2v(u2), h3 = up2v(u3);
        acc0 += h0 * a0; acc1 += h1 * a1; acc2 += h2 * a2; acc3 += h3 * a3;
        l0 += a0; l1 += a1; l2 += a2; l3 += a3;
    }
    for (; e < e1; e++) {
        int s = srcs[e];
        float a = (float)aH[e];
        f32x2 h = up2v(HSu[(s << 6) + lane]);
        acc0 += h * a;
        l0 += a;
    }
    f32x2 acc = (acc0 + acc1) + (acc2 + acc3);
    float l = (l0 + l1) + (l2 + l3);

    int j0 = lane * 2;
    float inv = 1.f / (l + 1e-16f);
    float o0 = acc.x * inv + bias[j0];
    float o1 = acc.y * inv + bias[j0 + 1];
    o0 = o0 > 0.f ? o0 : __expf(o0) - 1.f;   // ELU
    o1 = o1 > 0.f ? o1 : __expf(o1) - 1.f;
    *(float2*)&out[(size_t)d * DIM + j0] = make_float2(o0, o1);
}

// ---------------------------------------------------------------------------
extern "C" void kernel_launch(void* const* d_in, const int* in_sizes, int n_in,
                              void* d_out, int out_size, void* d_ws, size_t ws_size,
                              hipStream_t stream) {
    const float* x_food      = (const float*)d_in[0];
    const float* x_nut       = (const float*)d_in[1];
    const float* Wsrc_fn     = (const float*)d_in[2];
    const float* Wdst_fn     = (const float*)d_in[3];
    const float* att_src_fn  = (const float*)d_in[4];
    const float* att_dst_fn  = (const float*)d_in[5];
    const float* bias_fn     = (const float*)d_in[6];
    const float* Wsrc_nf     = (const float*)d_in[7];
    const float* Wdst_nf     = (const float*)d_in[8];
    const float* att_src_nf  = (const float*)d_in[9];
    const float* att_dst_nf  = (const float*)d_in[10];
    const float* bias_nf     = (const float*)d_in[11];
    const int*   ei_fn       = (const int*)d_in[12];
    const int*   ei_nf       = (const int*)d_in[13];
    float* out = (float*)d_out;

    char* ws = (char*)d_ws;
    size_t off = 0;
    auto alloc_f = [&](size_t n) { float* p = (float*)(ws + off); off += n * 4; return p; };
    auto alloc_i = [&](size_t n) { int* p = (int*)(ws + off); off += n * 4; return p; };
    auto alloc_h = [&](size_t n) { _Float16* p = (_Float16*)(ws + off); off += n * 2; return p; };
    auto alloc_u = [&](size_t n) { ushort* p = (ushort*)(ws + off); off += n * 2; return p; };

    float* B_food = alloc_f((size_t)NNODE * DIM);
    float* B_nut  = alloc_f((size_t)NNODE * DIM);
    ushort* HS_fn = alloc_u((size_t)NNODE * DIM);
    ushort* HS_nf = alloc_u((size_t)NNODE * DIM);
    float* AS_fn  = alloc_f(NNODE * NHEAD);
    float* AS_nf  = alloc_f(NNODE * NHEAD);
    float* AD_fn  = alloc_f(NNODE * NHEAD);
    float* AD_nf  = alloc_f(NNODE * NHEAD);
    float* wav    = alloc_f(4 * DIM * 8);
    _Float16* al_fn = alloc_h((size_t)NHEAD * NEDGE);
    _Float16* al_nf = alloc_h((size_t)NHEAD * NEDGE);
    int* ptr_fn   = alloc_i(50004);
    int* ptr_nf   = alloc_i(50004);
    ushort* srcs_fn = alloc_u(NEDGE);
    ushort* srcs_nf = alloc_u(NEDGE);
    ushort* dsts_fn = alloc_u(NEDGE);
    ushort* dsts_nf = alloc_u(NEDGE);
    int* bcnt     = alloc_i(512);
    unsigned* Mbuf = (unsigned*)alloc_i(16);   // [layer][rel][head]
    int* bko      = alloc_i(512);
    int* bcur     = alloc_i(512);
    // bkt buffers alias B_food/B_nut (dead until after CSR build)
    unsigned* bkt_fn = (unsigned*)B_food;
    unsigned* bkt_nf = (unsigned*)B_nut;

    // ---- CSR build: two-level counting sort (+ zero Mbuf, contiguous) ----
    hipMemsetAsync(bcnt, 0, (512 + 16) * 4, stream);
    bhist<<<2 * ECHUNK, 256, 0, stream>>>(ei_fn, ei_nf, bcnt);
    bscan<<<2, 256, 0, stream>>>(bcnt, bko, bcur, ptr_fn, ptr_nf);
    bscatter<<<2 * ECHUNK, 256, 0, stream>>>(ei_fn, ei_nf, bcur, bkt_fn, bkt_nf);
    bsort<<<2 * NBUCK, 256, 0, stream>>>(bkt_fn, bkt_nf, bko, ptr_fn, ptr_nf,
                                         srcs_fn, srcs_nf, dsts_fn, dsts_nf);

    prep_wav<<<4, 256, 0, stream>>>(Wsrc_fn, att_src_fn, Wdst_fn, att_dst_fn,
                                    Wsrc_nf, att_src_nf, Wdst_nf, att_dst_nf, wav);

    const int WL = DIM * DIM;
    const int TNB = 512;
    const int ANB = (NNODE + 3) / 4;
    float* wav0 = wav;
    float* wav1 = wav + DIM * 8;
    float* wav2 = wav + 2 * DIM * 8;
    float* wav3 = wav + 3 * DIM * 8;

    // ---- Layer 0 ----
    transform_kernel<<<2 * TNB, 256, 0, stream>>>(
        x_food, Wsrc_fn, wav0, HS_fn, AS_fn, AD_nf,
        x_nut,  Wsrc_nf, wav1, HS_nf, AS_nf, AD_fn, Mbuf, TNB);
    edge_alpha<<<2 * EB, 256, 0, stream>>>(
        srcs_fn, dsts_fn, AS_fn, AD_fn, al_fn,
        srcs_nf, dsts_nf, AS_nf, AD_nf, al_nf, Mbuf);
    agg_kernel<<<2 * ANB, 256, 0, stream>>>(
        HS_fn, al_fn, ptr_fn, srcs_fn, bias_fn, B_nut,
        HS_nf, al_nf, ptr_nf, srcs_nf, bias_nf, B_food, ANB);

    // ---- Layer 1 -> d_out ----
    transform_kernel<<<2 * TNB, 256, 0, stream>>>(
        B_food, Wsrc_fn + WL, wav2, HS_fn, AS_fn, AD_nf,
        B_nut,  Wsrc_nf + WL, wav3, HS_nf, AS_nf, AD_fn, Mbuf + 8, TNB);
    edge_alpha<<<2 * EB, 256, 0, stream>>>(
        srcs_fn, dsts_fn, AS_fn, AD_fn, al_fn,
        srcs_nf, dsts_nf, AS_nf, AD_nf, al_nf, Mbuf + 8);
    agg_kernel<<<2 * ANB, 256, 0, stream>>>(
        HS_fn, al_fn, ptr_fn, srcs_fn, bias_fn + DIM, out + (size_t)NNODE * DIM,
        HS_nf, al_nf, ptr_nf, srcs_nf, bias_nf + DIM, out, ANB);
}

// Round 6
// 465.726 us; speedup vs baseline: 2.2443x; 1.0603x over previous
//
#include <hip/hip_runtime.h>
#include <math.h>

#define NNODE 50000
#define NEDGE 800000
#define DIM   128
#define NHEAD 4
#define NTILE ((NNODE + 63) / 64)   // 782
#define NBUCK 196                    // ceil(NNODE/256) coarse buckets (dst>>8)
#define ECHUNK 196                   // ceil(NEDGE/4096) edge chunks
#define CAP   6144                   // per-bucket LDS sort capacity (mean 4082)
#define EB    (NEDGE / 256)          // 3125 edge blocks per relation

typedef __bf16 bf16x8 __attribute__((ext_vector_type(8)));
typedef float  f32x4  __attribute__((ext_vector_type(4)));
typedef float  f32x2  __attribute__((ext_vector_type(2)));

static __device__ __forceinline__ void bfsplit(float x, ushort& hi, ushort& lo) {
    __bf16 h = (__bf16)x;
    float hf = (float)h;
    __bf16 l = (__bf16)(x - hf);
    hi = __builtin_bit_cast(unsigned short, h);
    lo = __builtin_bit_cast(unsigned short, l);
}
static __device__ __forceinline__ ushort f2h(float x) {
    _Float16 h = (_Float16)x;
    return __builtin_bit_cast(unsigned short, h);
}
static __device__ __forceinline__ f32x2 up2v(unsigned u) {
    f32x2 r;
    r.x = (float)__builtin_bit_cast(_Float16, (unsigned short)(u & 0xffff));
    r.y = (float)__builtin_bit_cast(_Float16, (unsigned short)(u >> 16));
    return r;
}
// monotone float<->uint encoding for atomicMax on floats
static __device__ __forceinline__ unsigned encf(float f) {
    unsigned u = __builtin_bit_cast(unsigned, f);
    return (u >> 31) ? ~u : (u | 0x80000000u);
}
static __device__ __forceinline__ float decf(unsigned x) {
    unsigned u = (x >> 31) ? (x & 0x7fffffffu) : ~x;
    return __builtin_bit_cast(float, u);
}

// ---------------------------------------------------------------------------
// CSR build via two-level counting sort (no random 4B global scatters).
// ---------------------------------------------------------------------------
__global__ __launch_bounds__(256) void bhist(const int* __restrict__ eA,
                                             const int* __restrict__ eB,
                                             int* __restrict__ bcnt) {
    int rel = (int)(blockIdx.x >= ECHUNK);
    const int* dstrow = (rel ? eB : eA) + NEDGE;
    int blk = blockIdx.x - rel * ECHUNK;
    __shared__ int hist[256];
    hist[threadIdx.x] = 0;
    __syncthreads();
    int base = blk * 4096;
    #pragma unroll
    for (int k = 0; k < 16; k++) {
        int e = base + k * 256 + threadIdx.x;
        if (e < NEDGE) atomicAdd(&hist[dstrow[e] >> 8], 1);
    }
    __syncthreads();
    int h = hist[threadIdx.x];
    if (h) atomicAdd(&bcnt[rel * 256 + threadIdx.x], h);
}

__global__ __launch_bounds__(256) void bscan(const int* __restrict__ bcnt,
                                             int* __restrict__ bko, int* __restrict__ bcur,
                                             int* __restrict__ ptrA, int* __restrict__ ptrB) {
    int rel = blockIdx.x;
    __shared__ int tmp[256];
    int t = threadIdx.x;
    int v = bcnt[rel * 256 + t];
    tmp[t] = v; __syncthreads();
    for (int off = 1; off < 256; off <<= 1) {
        int a = (t >= off) ? tmp[t - off] : 0; __syncthreads();
        tmp[t] += a; __syncthreads();
    }
    int excl = tmp[t] - v;
    bko[rel * 256 + t] = excl;
    bcur[rel * 256 + t] = excl;
    if (t == 255) (rel ? ptrB : ptrA)[NNODE] = tmp[255];
}

__global__ __launch_bounds__(256) void bscatter(const int* __restrict__ eA,
                                                const int* __restrict__ eB,
                                                int* __restrict__ bcur,
                                                unsigned* __restrict__ bktA,
                                                unsigned* __restrict__ bktB) {
    int rel = (int)(blockIdx.x >= ECHUNK);
    const int* ebase = rel ? eB : eA;
    unsigned* bkt = rel ? bktB : bktA;
    int blk = blockIdx.x - rel * ECHUNK;
    __shared__ int hist[256], bas[256], cur[256];
    hist[threadIdx.x] = 0;
    __syncthreads();
    int base = blk * 4096;
    #pragma unroll
    for (int k = 0; k < 16; k++) {
        int e = base + k * 256 + threadIdx.x;
        if (e < NEDGE) atomicAdd(&hist[ebase[NEDGE + e] >> 8], 1);
    }
    __syncthreads();
    int h = hist[threadIdx.x];
    bas[threadIdx.x] = h ? atomicAdd(&bcur[rel * 256 + threadIdx.x], h) : 0;
    cur[threadIdx.x] = 0;
    __syncthreads();
    #pragma unroll
    for (int k = 0; k < 16; k++) {
        int e = base + k * 256 + threadIdx.x;
        if (e < NEDGE) {
            int s = ebase[e], d = ebase[NEDGE + e];
            int b = d >> 8;
            int loc = atomicAdd(&cur[b], 1);
            bkt[bas[b] + loc] = ((unsigned)(d & 255) << 16) | (unsigned)s;
        }
    }
}

// per-bucket exact sort in LDS -> coalesced srcs/dsts (ushort) + ptr for free
__global__ __launch_bounds__(256) void bsort(const unsigned* __restrict__ bktA,
                                             const unsigned* __restrict__ bktB,
                                             const int* __restrict__ bko,
                                             int* __restrict__ ptrA, int* __restrict__ ptrB,
                                             ushort* __restrict__ srcA, ushort* __restrict__ srcB,
                                             ushort* __restrict__ dstA, ushort* __restrict__ dstB) {
    int rel = (int)(blockIdx.x >= NBUCK);
    const unsigned* bkt = rel ? bktB : bktA;
    int* ptr   = rel ? ptrB : ptrA;
    ushort* srcs = rel ? srcB : srcA;
    ushort* dsts = rel ? dstB : dstA;
    int b = blockIdx.x - rel * NBUCK;
    int beg = bko[rel * 256 + b], end = bko[rel * 256 + b + 1];
    int cnt_e = end - beg;
    __shared__ int hist[256], excl[256], cur[256];
    __shared__ unsigned sorted[CAP];
    int t = threadIdx.x;
    hist[t] = 0;
    __syncthreads();
    for (int i = t; i < cnt_e; i += 256) atomicAdd(&hist[bkt[beg + i] >> 16], 1);
    __syncthreads();
    int v = hist[t];
    excl[t] = v; __syncthreads();
    for (int off = 1; off < 256; off <<= 1) {
        int a = (t >= off) ? excl[t - off] : 0; __syncthreads();
        excl[t] += a; __syncthreads();
    }
    int ex = excl[t] - v;
    int d = b * 256 + t;
    if (d < NNODE) ptr[d] = beg + ex;
    cur[t] = ex;
    __syncthreads();
    for (int i = t; i < cnt_e; i += 256) {
        unsigned u = bkt[beg + i];
        int dl = u >> 16;
        int p = atomicAdd(&cur[dl], 1);
        if (p < CAP) sorted[p] = u;
        else {  // statistically unreachable overflow fallback
            srcs[beg + p] = (ushort)(u & 0xffffu);
            dsts[beg + p] = (ushort)(b * 256 + dl);
        }
    }
    __syncthreads();
    int lim = cnt_e < CAP ? cnt_e : CAP;
    for (int i = t; i < lim; i += 256) {
        unsigned u = sorted[i];
        srcs[beg + i] = (ushort)(u & 0xffffu);
        dsts[beg + i] = (ushort)(b * 256 + (u >> 16));
    }
}

// ---------------------------------------------------------------------------
// wav[call][k][8]: cols 0..3 = was (Wsrc·a_src), 4..7 = wad (Wdst·a_dst)
// ---------------------------------------------------------------------------
__global__ void prep_wav(const float* __restrict__ Wsrc_fn, const float* __restrict__ a_src_fn,
                         const float* __restrict__ Wdst_fn, const float* __restrict__ a_dst_fn,
                         const float* __restrict__ Wsrc_nf, const float* __restrict__ a_src_nf,
                         const float* __restrict__ Wdst_nf, const float* __restrict__ a_dst_nf,
                         float* __restrict__ wav) {
    int call = blockIdx.x;
    int layer = call >> 1, which = call & 1;
    const float* Ws = which ? Wsrc_nf : Wsrc_fn;
    const float* as = which ? a_src_nf : a_src_fn;
    const float* Wd = which ? Wdst_fn : Wdst_nf;
    const float* ad = which ? a_dst_fn : a_dst_nf;
    Ws += layer * DIM * DIM; Wd += layer * DIM * DIM;
    as += layer * DIM; ad += layer * DIM;
    for (int it = threadIdx.x; it < 512; it += 256) {
        int k = it >> 2, h = it & 3;
        float s = 0.f, dv = 0.f;
        #pragma unroll 8
        for (int c = 0; c < 32; c++) {
            s  += Ws[k * DIM + h * 32 + c] * as[h * 32 + c];
            dv += Wd[k * DIM + h * 32 + c] * ad[h * 32 + c];
        }
        float* o = wav + (size_t)call * DIM * 8 + k * 8;
        o[h] = s; o[h + 4] = dv;
    }
}

// ---------------------------------------------------------------------------
// Transform (split-bf16 MFMA): HS(fp16) = X @ W ; [AS|AD] = X @ wav (MFMA too)
// X A-fragments loaded straight from global into registers (no LDS staging,
// no per-tile barrier). W^T and wav^T hi/lo staged in LDS once per block.
// Block = 4 waves, 64 rows/tile, 64-col half of W per block (half = vb&1).
// ---------------------------------------------------------------------------
__global__ __launch_bounds__(256, 3) void transform_kernel(
    const float* __restrict__ XA, const float* __restrict__ WA, const float* __restrict__ wavA,
    ushort* __restrict__ HSA, float* __restrict__ ASA, float* __restrict__ ADA,
    const float* __restrict__ XB, const float* __restrict__ WB, const float* __restrict__ wavB,
    ushort* __restrict__ HSB, float* __restrict__ ASB, float* __restrict__ ADB,
    unsigned* __restrict__ Mg, int nb)
{
    int rel = (int)(blockIdx.x >= (unsigned)nb);
    const float* X  = rel ? XB : XA;
    const float* W  = rel ? WB : WA;
    const float* wav = rel ? wavB : wavA;
    ushort* HS = rel ? HSB : HSA;
    float*  AS = rel ? ASB : ASA;
    float*  AD = rel ? ADB : ADA;

    __shared__ ushort WTh[64][136], WTl[64][136];     // W^T[col][k] hi/lo
    __shared__ ushort wavTh[16][136], wavTl[16][136]; // wav^T[oi][k], oi>=8 zero
    __shared__ unsigned mloc[4];

    int vb = blockIdx.x - rel * nb;
    int half = vb & 1;
    int ch = half * 64;

    for (int i = threadIdx.x; i < 64 * DIM; i += 256) {
        int col = i & 63, k = i >> 6;
        ushort hi, lo; bfsplit(W[k * DIM + ch + col], hi, lo);
        WTh[col][k] = hi; WTl[col][k] = lo;
    }
    for (int i = threadIdx.x; i < 16 * DIM; i += 256) {
        int c = i & 15, k = i >> 4;
        float w = (c < 8) ? wav[k * 8 + c] : 0.f;
        ushort hi, lo; bfsplit(w, hi, lo);
        wavTh[c][k] = hi; wavTl[c][k] = lo;
    }
    if (threadIdx.x < 4) mloc[threadIdx.x] = 0;
    __syncthreads();

    const int wv = threadIdx.x >> 6, lane = threadIdx.x & 63;
    const int lm = lane & 15, lq = lane >> 4;
    const int r0 = wv * 16;

    for (int tile = vb >> 1; tile < NTILE; tile += (nb >> 1)) {
        int row0 = tile * 64;
        int myrow = row0 + r0 + lm;
        int rowc = myrow < NNODE ? myrow : NNODE - 1;   // clamp (dup is harmless)
        const float4* Xr = (const float4*)(X + (size_t)rowc * DIM);

        // load this lane's full A-row slice: 8 float4 (k = kc*32 + lq*8 .. +8)
        float4 xv[8];
        #pragma unroll
        for (int kc = 0; kc < 4; kc++) {
            xv[kc * 2]     = Xr[kc * 8 + lq * 2];
            xv[kc * 2 + 1] = Xr[kc * 8 + lq * 2 + 1];
        }

        f32x4 acc[4] = {{0,0,0,0},{0,0,0,0},{0,0,0,0},{0,0,0,0}};
        f32x4 accv = {0,0,0,0};
        #pragma unroll
        for (int kc = 0; kc < 4; kc++) {
            const float* fp = (const float*)&xv[kc * 2];
            bf16x8 ah, al;
            #pragma unroll
            for (int j = 0; j < 8; j++) {
                float x = fp[j];
                __bf16 h = (__bf16)x;
                ah[j] = h;
                al[j] = (__bf16)(x - (float)h);
            }
            int k0 = kc * 32 + lq * 8;
            #pragma unroll
            for (int ct = 0; ct < 4; ct++) {
                bf16x8 bh = *(const bf16x8*)&WTh[ct * 16 + lm][k0];
                bf16x8 bl = *(const bf16x8*)&WTl[ct * 16 + lm][k0];
                acc[ct] = __builtin_amdgcn_mfma_f32_16x16x32_bf16(al, bh, acc[ct], 0, 0, 0);
                acc[ct] = __builtin_amdgcn_mfma_f32_16x16x32_bf16(ah, bl, acc[ct], 0, 0, 0);
                acc[ct] = __builtin_amdgcn_mfma_f32_16x16x32_bf16(ah, bh, acc[ct], 0, 0, 0);
            }
            if (half == 0) {
                bf16x8 vh = *(const bf16x8*)&wavTh[lm][k0];
                bf16x8 vl = *(const bf16x8*)&wavTl[lm][k0];
                accv = __builtin_amdgcn_mfma_f32_16x16x32_bf16(al, vh, accv, 0, 0, 0);
                accv = __builtin_amdgcn_mfma_f32_16x16x32_bf16(ah, vl, accv, 0, 0, 0);
                accv = __builtin_amdgcn_mfma_f32_16x16x32_bf16(ah, vh, accv, 0, 0, 0);
            }
        }

        // HS stores; C/D layout: col = lm, row = lq*4 + r
        #pragma unroll
        for (int ct = 0; ct < 4; ct++) {
            #pragma unroll
            for (int r = 0; r < 4; r++) {
                int row = row0 + r0 + lq * 4 + r;
                if (row < NNODE) HS[(size_t)row * DIM + ch + ct * 16 + lm] = f2h(acc[ct][r]);
            }
        }
        // AS/AD stores (half-0 blocks only); lanes lm<8 hold the 8 outputs
        if (half == 0 && lm < 8) {
            float mx4 = -INFINITY;
            #pragma unroll
            for (int r = 0; r < 4; r++) {
                int row = row0 + r0 + lq * 4 + r;
                if (row < NNODE) {
                    if (lm < 4) AS[row * 4 + lm] = accv[r];
                    else        AD[row * 4 + (lm - 4)] = accv[r];
                }
                mx4 = fmaxf(mx4, accv[r]);
            }
            if (lm < 4) atomicMax(&mloc[lm], encf(mx4));
        }
    }
    __syncthreads();
    if (half == 0 && threadIdx.x < 4)
        atomicMax(&Mg[rel * 4 + threadIdx.x], mloc[threadIdx.x]);
}

// ---------------------------------------------------------------------------
// Edge-parallel alpha: alpha[h][e] = exp(lrelu(AS[s,h]+AD[d,h]) - m_{d,h}),
// m_{d,h} = lrelu(maxAS_h + AD[d,h]) >= segment max (softmax shift-invariant).
// ---------------------------------------------------------------------------
__global__ __launch_bounds__(256) void edge_alpha(
    const ushort* __restrict__ srcA, const ushort* __restrict__ dstA,
    const float* __restrict__ ASA, const float* __restrict__ ADA,
    _Float16* __restrict__ alA,
    const ushort* __restrict__ srcB, const ushort* __restrict__ dstB,
    const float* __restrict__ ASB, const float* __restrict__ ADB,
    _Float16* __restrict__ alB,
    const unsigned* __restrict__ Mg)
{
    int rel = (int)(blockIdx.x >= EB);
    const ushort* srcs = rel ? srcB : srcA;
    const ushort* dsts = rel ? dstB : dstA;
    const float* AS = rel ? ASB : ASA;
    const float* AD = rel ? ADB : ADA;
    _Float16* al = rel ? alB : alA;
    float mx[4];
    #pragma unroll
    for (int h = 0; h < 4; h++) mx[h] = decf(Mg[rel * 4 + h]);
    int e = (blockIdx.x - rel * EB) * 256 + threadIdx.x;
    int s = srcs[e], d = dsts[e];
    f32x4 as4 = ((const f32x4*)AS)[s];
    f32x4 ad4 = ((const f32x4*)AD)[d];
    #pragma unroll
    for (int h = 0; h < 4; h++) {
        float v = as4[h] + ad4[h];
        v = v > 0.f ? v : 0.2f * v;
        float mm = mx[h] + ad4[h];
        mm = mm > 0.f ? mm : 0.2f * mm;
        al[h * NEDGE + e] = (_Float16)__expf(v - mm);
    }
}

// ---------------------------------------------------------------------------
// Aggregation: one wave per dst node; sequential alpha + srcs, HS gather,
// packed f32x2 FMA. No softmax math in the loop. Fuses bias + ELU.
// ---------------------------------------------------------------------------
__global__ __launch_bounds__(256) void agg_kernel(
    const ushort* __restrict__ HSA, const _Float16* __restrict__ alA,
    const int* __restrict__ ptrA, const ushort* __restrict__ srcA,
    const float* __restrict__ biasA, float* __restrict__ outA,
    const ushort* __restrict__ HSB, const _Float16* __restrict__ alB,
    const int* __restrict__ ptrB, const ushort* __restrict__ srcB,
    const float* __restrict__ biasB, float* __restrict__ outB, int nb)
{
    int rel = (int)(blockIdx.x >= (unsigned)nb);
    const unsigned* HSu = (const unsigned*)(rel ? HSB : HSA);
    const ushort* srcs = rel ? srcB : srcA;
    const int* ptr = rel ? ptrB : ptrA;
    const float* bias = rel ? biasB : biasA;
    float* out = rel ? outB : outA;

    int bid = blockIdx.x - rel * nb;
    int wave = threadIdx.x >> 6, lane = threadIdx.x & 63;
    int d = bid * 4 + wave;
    if (d >= NNODE) return;
    int hh = lane >> 4;
    const _Float16* aH = (rel ? alB : alA) + hh * NEDGE;
    int e0 = ptr[d], e1 = ptr[d + 1];

    f32x2 acc0 = {0.f, 0.f}, acc1 = acc0, acc2 = acc0, acc3 = acc0;
    float l0 = 0.f, l1 = 0.f, l2 = 0.f, l3 = 0.f;
    int e = e0;
    for (; e + 4 <= e1; e += 4) {
        int s0 = srcs[e], s1 = srcs[e + 1], s2 = srcs[e + 2], s3 = srcs[e + 3];
        float a0 = (float)aH[e], a1 = (float)aH[e + 1];
        float a2 = (float)aH[e + 2], a3 = (float)aH[e + 3];
        unsigned u0 = HSu[(s0 << 6) + lane];
        unsigned u1 = HSu[(s1 << 6) + lane];
        unsigned u2 = HSu[(s2 << 6) + lane];
        unsigned u3 = HSu[(s3 << 6) + lane];
        f32x2 h0 = up2v(u0), h1 = up2v(u1), h2 = up2v(u2), h3 = up2v(u3);
        acc0 += h0 * a0; acc1 += h1 * a1; acc2 += h2 * a2; acc3 += h3 * a3;
        l0 += a0; l1 += a1; l2 += a2; l3 += a3;
    }
    for (; e < e1; e++) {
        int s = srcs[e];
        float a = (float)aH[e];
        f32x2 h = up2v(HSu[(s << 6) + lane]);
        acc0 += h * a;
        l0 += a;
    }
    f32x2 acc = (acc0 + acc1) + (acc2 + acc3);
    float l = (l0 + l1) + (l2 + l3);

    int j0 = lane * 2;
    float inv = 1.f / (l + 1e-16f);
    float o0 = acc.x * inv + bias[j0];
    float o1 = acc.y * inv + bias[j0 + 1];
    o0 = o0 > 0.f ? o0 : __expf(o0) - 1.f;   // ELU
    o1 = o1 > 0.f ? o1 : __expf(o1) - 1.f;
    *(float2*)&out[(size_t)d * DIM + j0] = make_float2(o0, o1);
}

// ---------------------------------------------------------------------------
extern "C" void kernel_launch(void* const* d_in, const int* in_sizes, int n_in,
                              void* d_out, int out_size, void* d_ws, size_t ws_size,
                              hipStream_t stream) {
    const float* x_food      = (const float*)d_in[0];
    const float* x_nut       = (const float*)d_in[1];
    const float* Wsrc_fn     = (const float*)d_in[2];
    const float* Wdst_fn     = (const float*)d_in[3];
    const float* att_src_fn  = (const float*)d_in[4];
    const float* att_dst_fn  = (const float*)d_in[5];
    const float* bias_fn     = (const float*)d_in[6];
    const float* Wsrc_nf     = (const float*)d_in[7];
    const float* Wdst_nf     = (const float*)d_in[8];
    const float* att_src_nf  = (const float*)d_in[9];
    const float* att_dst_nf  = (const float*)d_in[10];
    const float* bias_nf     = (const float*)d_in[11];
    const int*   ei_fn       = (const int*)d_in[12];
    const int*   ei_nf       = (const int*)d_in[13];
    float* out = (float*)d_out;

    char* ws = (char*)d_ws;
    size_t off = 0;
    auto alloc_f = [&](size_t n) { float* p = (float*)(ws + off); off += n * 4; return p; };
    auto alloc_i = [&](size_t n) { int* p = (int*)(ws + off); off += n * 4; return p; };
    auto alloc_h = [&](size_t n) { _Float16* p = (_Float16*)(ws + off); off += n * 2; return p; };
    auto alloc_u = [&](size_t n) { ushort* p = (ushort*)(ws + off); off += n * 2; return p; };

    float* B_food = alloc_f((size_t)NNODE * DIM);
    float* B_nut  = alloc_f((size_t)NNODE * DIM);
    ushort* HS_fn = alloc_u((size_t)NNODE * DIM);
    ushort* HS_nf = alloc_u((size_t)NNODE * DIM);
    float* AS_fn  = alloc_f(NNODE * NHEAD);
    float* AS_nf  = alloc_f(NNODE * NHEAD);
    float* AD_fn  = alloc_f(NNODE * NHEAD);
    float* AD_nf  = alloc_f(NNODE * NHEAD);
    float* wav    = alloc_f(4 * DIM * 8);
    _Float16* al_fn = alloc_h((size_t)NHEAD * NEDGE);
    _Float16* al_nf = alloc_h((size_t)NHEAD * NEDGE);
    int* ptr_fn   = alloc_i(50004);
    int* ptr_nf   = alloc_i(50004);
    ushort* srcs_fn = alloc_u(NEDGE);
    ushort* srcs_nf = alloc_u(NEDGE);
    ushort* dsts_fn = alloc_u(NEDGE);
    ushort* dsts_nf = alloc_u(NEDGE);
    int* bcnt     = alloc_i(512);
    unsigned* Mbuf = (unsigned*)alloc_i(16);   // [layer][rel][head]
    int* bko      = alloc_i(512);
    int* bcur     = alloc_i(512);
    // bkt buffers alias B_food/B_nut (dead until after CSR build)
    unsigned* bkt_fn = (unsigned*)B_food;
    unsigned* bkt_nf = (unsigned*)B_nut;

    // ---- CSR build: two-level counting sort (+ zero Mbuf, contiguous) ----
    hipMemsetAsync(bcnt, 0, (512 + 16) * 4, stream);
    bhist<<<2 * ECHUNK, 256, 0, stream>>>(ei_fn, ei_nf, bcnt);
    bscan<<<2, 256, 0, stream>>>(bcnt, bko, bcur, ptr_fn, ptr_nf);
    bscatter<<<2 * ECHUNK, 256, 0, stream>>>(ei_fn, ei_nf, bcur, bkt_fn, bkt_nf);
    bsort<<<2 * NBUCK, 256, 0, stream>>>(bkt_fn, bkt_nf, bko, ptr_fn, ptr_nf,
                                         srcs_fn, srcs_nf, dsts_fn, dsts_nf);

    prep_wav<<<4, 256, 0, stream>>>(Wsrc_fn, att_src_fn, Wdst_fn, att_dst_fn,
                                    Wsrc_nf, att_src_nf, Wdst_nf, att_dst_nf, wav);

    const int WL = DIM * DIM;
    const int TNB = 768;
    const int ANB = (NNODE + 3) / 4;
    float* wav0 = wav;
    float* wav1 = wav + DIM * 8;
    float* wav2 = wav + 2 * DIM * 8;
    float* wav3 = wav + 3 * DIM * 8;

    // ---- Layer 0 ----
    transform_kernel<<<2 * TNB, 256, 0, stream>>>(
        x_food, Wsrc_fn, wav0, HS_fn, AS_fn, AD_nf,
        x_nut,  Wsrc_nf, wav1, HS_nf, AS_nf, AD_fn, Mbuf, TNB);
    edge_alpha<<<2 * EB, 256, 0, stream>>>(
        srcs_fn, dsts_fn, AS_fn, AD_fn, al_fn,
        srcs_nf, dsts_nf, AS_nf, AD_nf, al_nf, Mbuf);
    agg_kernel<<<2 * ANB, 256, 0, stream>>>(
        HS_fn, al_fn, ptr_fn, srcs_fn, bias_fn, B_nut,
        HS_nf, al_nf, ptr_nf, srcs_nf, bias_nf, B_food, ANB);

    // ---- Layer 1 -> d_out ----
    transform_kernel<<<2 * TNB, 256, 0, stream>>>(
        B_food, Wsrc_fn + WL, wav2, HS_fn, AS_fn, AD_nf,
        B_nut,  Wsrc_nf + WL, wav3, HS_nf, AS_nf, AD_fn, Mbuf + 8, TNB);
    edge_alpha<<<2 * EB, 256, 0, stream>>>(
        srcs_fn, dsts_fn, AS_fn, AD_fn, al_fn,
        srcs_nf, dsts_nf, AS_nf, AD_nf, al_nf, Mbuf + 8);
    agg_kernel<<<2 * ANB, 256, 0, stream>>>(
        HS_fn, al_fn, ptr_fn, srcs_fn, bias_fn + DIM, out + (size_t)NNODE * DIM,
        HS_nf, al_nf, ptr_nf, srcs_nf, bias_nf + DIM, out, ANB);
}